// Round 1
// baseline (322.068 us; speedup 1.0000x reference)
//
#include <hip/hip_runtime.h>

// Problem constants
#define Bz   32
#define Nn   1024
#define Dd   128
#define OUTW 64

typedef __attribute__((ext_vector_type(8))) short bf16x8;  // 8 bf16 = 4 VGPR
typedef __attribute__((ext_vector_type(4))) short bf16x4;  // 4 bf16 = 8B
typedef __attribute__((ext_vector_type(4))) float f32x4;

static __device__ __forceinline__ unsigned short f2bf(float x) {
    unsigned u = __float_as_uint(x);
    u += 0x7FFFu + ((u >> 16) & 1u);            // round-to-nearest-even
    return (unsigned short)(u >> 16);
}
static __device__ __forceinline__ float bf2f(short b) {
    return __uint_as_float(((unsigned)(unsigned short)b) << 16);
}

// ---------------------------------------------------------------------------
// Kernel 1: L2-normalize rows of drug_1/drug_2, emit bf16 copies for MFMA.
// One wave per 128-elem row.
__global__ __launch_bounds__(256) void k_norm(const float* __restrict__ d1,
                                              const float* __restrict__ d2,
                                              short* __restrict__ d1b,
                                              short* __restrict__ d2b) {
    const int wave = threadIdx.x >> 6, lane = threadIdx.x & 63;
    const int row = blockIdx.x * 4 + wave;            // 0..65535
    const float* src; short* dst; int r;
    if (row < Bz * Nn) { src = d1; dst = d1b; r = row; }
    else               { src = d2; dst = d2b; r = row - Bz * Nn; }
    const float2 v = *(const float2*)(src + (long)r * Dd + lane * 2);
    float ss = v.x * v.x + v.y * v.y;
    #pragma unroll
    for (int msk = 1; msk < 64; msk <<= 1) ss += __shfl_xor(ss, msk, 64);
    const float inv = 1.0f / fmaxf(sqrtf(ss), 1e-12f);
    short2 o;
    o.x = (short)f2bf(v.x * inv);
    o.y = (short)f2bf(v.y * inv);
    *(short2*)(dst + (long)r * Dd + lane * 2) = o;
}

// ---------------------------------------------------------------------------
// Kernel 2: dual-direction flash attention (no online max needed: aff in
// [-0.5,0.5]).  Block = 4 waves, each wave owns 16 Q rows; KV tile = 32.
// blockIdx.z selects direction.
#define VST 40   // LDS row stride in bf16 elems (80B): keeps b128 reads 16B-aligned
__global__ __launch_bounds__(256) void k_attn(const short* __restrict__ d1b,
                                              const short* __restrict__ d2b,
                                              float* __restrict__ layerA,
                                              float* __restrict__ layerB) {
    __shared__ __attribute__((aligned(16))) short Vt[Dd][VST];     // V^T tile, 10240 B
    __shared__ __attribute__((aligned(16))) short Pl[4][16][VST];  // per-wave P, 5120 B

    const short* Q; const short* K; float* O;
    if (blockIdx.z == 0) { Q = d1b; K = d2b; O = layerA; }
    else                 { Q = d2b; K = d1b; O = layerB; }

    const int tid  = threadIdx.x;
    const int wave = tid >> 6;
    const int lane = tid & 63;
    const int m = lane & 15, g = lane >> 4;
    const int b  = blockIdx.y;
    const int q0 = blockIdx.x * 64 + wave * 16;

    const short* Qb = Q + ((long)b * Nn + q0) * Dd;
    const short* Kb = K + (long)b * Nn * Dd;

    // Q A-frags: lane holds Q[q0+m][c*32 + g*8 + j]
    bf16x8 qf[4];
    #pragma unroll
    for (int c = 0; c < 4; ++c)
        qf[c] = *(const bf16x8*)(Qb + m * Dd + c * 32 + g * 8);

    f32x4 oacc[8];
    #pragma unroll
    for (int t = 0; t < 8; ++t) oacc[t] = (f32x4){0.f, 0.f, 0.f, 0.f};
    float lsum[4] = {0.f, 0.f, 0.f, 0.f};

    const int vrow = tid >> 3;          // 0..31: kv row within tile
    const int vd   = (tid & 7) * 16;    // d-offset this thread transposes

    for (int kv0 = 0; kv0 < Nn; kv0 += 32) {
        __syncthreads();   // previous iteration's PV reads of Vt/Pl are done
        // ---- stage V^T into LDS (each thread: 16 elems of one kv row) ----
        {
            const short* vs = Kb + (long)(kv0 + vrow) * Dd + vd;
            bf16x8 va = *(const bf16x8*)vs;
            bf16x8 vb = *(const bf16x8*)(vs + 8);
            #pragma unroll
            for (int e = 0; e < 8; ++e) Vt[vd + e][vrow] = va[e];
            #pragma unroll
            for (int e = 0; e < 8; ++e) Vt[vd + 8 + e][vrow] = vb[e];
        }
        // ---- S = Q · K^T  (two 16-col n-tiles, K-dim 128 in 4 chunks) ----
        f32x4 s0 = (f32x4){0.f, 0.f, 0.f, 0.f};
        f32x4 s1 = (f32x4){0.f, 0.f, 0.f, 0.f};
        const short* kr0 = Kb + (long)(kv0 + m) * Dd + g * 8;
        const short* kr1 = kr0 + 16 * Dd;
        #pragma unroll
        for (int c = 0; c < 4; ++c) {
            bf16x8 kf = *(const bf16x8*)(kr0 + c * 32);
            s0 = __builtin_amdgcn_mfma_f32_16x16x32_bf16(qf[c], kf, s0, 0, 0, 0);
        }
        #pragma unroll
        for (int c = 0; c < 4; ++c) {
            bf16x8 kf = *(const bf16x8*)(kr1 + c * 32);
            s1 = __builtin_amdgcn_mfma_f32_16x16x32_bf16(qf[c], kf, s1, 0, 0, 0);
        }
        // ---- P = exp(0.5*s); bf16 to LDS; accumulate row sums (bf16-consistent)
        #pragma unroll
        for (int r = 0; r < 4; ++r) {
            const float p0 = exp2f(s0[r] * 0.72134752044448169f); // 0.5*log2(e)
            const float p1 = exp2f(s1[r] * 0.72134752044448169f);
            const unsigned short b0 = f2bf(p0), b1 = f2bf(p1);
            Pl[wave][4 * g + r][m]      = (short)b0;   // D-layout: row=4g+r, col=m
            Pl[wave][4 * g + r][16 + m] = (short)b1;
            lsum[r] += bf2f((short)b0) + bf2f((short)b1);
        }
        __syncthreads();   // Vt + Pl visible
        // ---- O += P · V ----
        bf16x8 pf = *(const bf16x8*)&Pl[wave][m][g * 8];   // A-frag of P
        #pragma unroll
        for (int t = 0; t < 8; ++t) {
            bf16x8 vf = *(const bf16x8*)&Vt[t * 16 + m][g * 8]; // B-frag of V
            oacc[t] = __builtin_amdgcn_mfma_f32_16x16x32_bf16(pf, vf, oacc[t], 0, 0, 0);
        }
    }

    // reduce row sums across the 16 lanes sharing g (cols of the row)
    #pragma unroll
    for (int r = 0; r < 4; ++r) {
        #pragma unroll
        for (int msk = 1; msk < 16; msk <<= 1)
            lsum[r] += __shfl_xor(lsum[r], msk, 64);
    }
    float* ob = O + ((long)b * Nn + q0) * Dd;
    #pragma unroll
    for (int r = 0; r < 4; ++r) {
        const float inv = 1.0f / lsum[r];
        #pragma unroll
        for (int t = 0; t < 8; ++t)
            ob[(4 * g + r) * Dd + t * 16 + m] = oacc[t][r] * inv;
    }
}

// ---------------------------------------------------------------------------
// Kernel 3: fusion row -> fc1(256->64) + relu + softmax(64) ; pooled*w.
// One wave per fusion row; lane = output channel. W staged bf16 in LDS.
__global__ __launch_bounds__(256) void k_fuse(const float* __restrict__ drug1,
                                              const float* __restrict__ drug2,
                                              const float* __restrict__ layerA,
                                              const float* __restrict__ layerB,
                                              const float* __restrict__ fc1w,
                                              const float* __restrict__ fc1b,
                                              float* __restrict__ out) {
    __shared__ __attribute__((aligned(16))) short Wl[OUTW][260]; // bf16, padded stride
    __shared__ __attribute__((aligned(16))) float fus[4][256];   // per-wave fusion row
    const int tid = threadIdx.x, wave = tid >> 6, lane = tid & 63;

    for (int i = tid; i < OUTW * 256; i += 256)
        Wl[i >> 8][i & 255] = (short)f2bf(fc1w[i]);
    const float bias = fc1b[lane];
    __syncthreads();

    for (int rep = 0; rep < 16; ++rep) {
        const int row = blockIdx.x * 64 + wave * 16 + rep;  // 0..65535
        const int bb = row >> 11;
        const int i  = row & 2047;
        const float* src; const float* lay; int n;
        if (i < Nn) { src = drug1; lay = layerA; n = i; }
        else        { src = drug2; lay = layerB; n = i - Nn; }
        const long base = ((long)bb * Nn + n) * Dd + lane * 2;
        const float2 v  = *(const float2*)(src + base);
        const float2 lv = *(const float2*)(lay + base);
        float ss = v.x * v.x + v.y * v.y;
        #pragma unroll
        for (int msk = 1; msk < 64; msk <<= 1) ss += __shfl_xor(ss, msk, 64);
        const float inv = 1.0f / fmaxf(sqrtf(ss), 1e-12f);
        fus[wave][lane * 2]           = v.x * inv;
        fus[wave][lane * 2 + 1]       = v.y * inv;
        fus[wave][128 + lane * 2]     = lv.x;
        fus[wave][128 + lane * 2 + 1] = lv.y;
        __syncthreads();
        // fc1: lane computes output channel `lane`
        float acc = bias;
        #pragma unroll 16
        for (int f4 = 0; f4 < 64; ++f4) {
            const float4 fv = *(const float4*)&fus[wave][f4 * 4];   // broadcast read
            const bf16x4 wv = *(const bf16x4*)&Wl[lane][f4 * 4];
            acc += fv.x * bf2f(wv[0]) + fv.y * bf2f(wv[1])
                 + fv.z * bf2f(wv[2]) + fv.w * bf2f(wv[3]);
        }
        acc = fmaxf(acc, 0.0f);
        float mx = acc;
        #pragma unroll
        for (int msk = 1; msk < 64; msk <<= 1) mx = fmaxf(mx, __shfl_xor(mx, msk, 64));
        const float e = exp2f((acc - mx) * 1.4426950408889634f);
        float sum = e;
        #pragma unroll
        for (int msk = 1; msk < 64; msk <<= 1) sum += __shfl_xor(sum, msk, 64);
        const float w = e / sum;
        const float4 pv = *(const float4*)&fus[wave][lane * 4];     // AvgPool1d(4)
        const float pooled = 0.25f * (pv.x + pv.y + pv.z + pv.w);
        out[(long)row * OUTW + lane] = pooled * w;
    }
}

// ---------------------------------------------------------------------------
extern "C" void kernel_launch(void* const* d_in, const int* in_sizes, int n_in,
                              void* d_out, int out_size, void* d_ws, size_t ws_size,
                              hipStream_t stream) {
    const float* drug1 = (const float*)d_in[0];
    const float* drug2 = (const float*)d_in[1];
    const float* fc1w  = (const float*)d_in[2];
    const float* fc1b  = (const float*)d_in[3];
    float* out = (float*)d_out;

    // workspace layout (48 MB total)
    char* ws = (char*)d_ws;
    short* d1b   = (short*)ws;                    // 8 MB bf16 normalized drug_1
    short* d2b   = (short*)(ws + 8388608);        // 8 MB bf16 normalized drug_2
    float* layerA = (float*)(ws + 16777216);      // 16 MB drug2_layer (attn d1->d2)
    float* layerB = (float*)(ws + 33554432);      // 16 MB drug1_layer (attn d2->d1)

    hipLaunchKernelGGL(k_norm, dim3(16384), dim3(256), 0, stream,
                       drug1, drug2, d1b, d2b);
    hipLaunchKernelGGL(k_attn, dim3(16, 32, 2), dim3(256), 0, stream,
                       d1b, d2b, layerA, layerB);
    hipLaunchKernelGGL(k_fuse, dim3(1024), dim3(256), 0, stream,
                       drug1, drug2, layerA, layerB, fc1w, fc1b, out);
}

// Round 2
// 320.510 us; speedup vs baseline: 1.0049x; 1.0049x over previous
//
#include <hip/hip_runtime.h>

#define Bz   32
#define Nn   1024
#define Dd   128
#define OUTW 64
#define CEXP 0.72134752044448169f   // 0.5 * log2(e)

typedef __attribute__((ext_vector_type(8))) short bf16x8;  // 8 bf16 = 4 VGPR
typedef __attribute__((ext_vector_type(4))) short bf16x4;
typedef __attribute__((ext_vector_type(4))) float f32x4;

static __device__ __forceinline__ unsigned short f2bf(float x) {
    unsigned u = __float_as_uint(x);
    u += 0x7FFFu + ((u >> 16) & 1u);            // RNE
    return (unsigned short)(u >> 16);
}
static __device__ __forceinline__ float bf2f(short b) {
    return __uint_as_float(((unsigned)(unsigned short)b) << 16);
}
static __device__ __forceinline__ unsigned cvt_pk_bf16(float lo, float hi) {
    unsigned r;
    asm("v_cvt_pk_bf16_f32 %0, %1, %2" : "=v"(r) : "v"(lo), "v"(hi));
    return r;
}

// ---------------------------------------------------------------------------
// Kernel 1: L2-normalize + emit bf16 row-major AND transposed [B][D][N] copies.
// Block: 64-row x 128-d tile of one matrix/batch. 4 threads per row.
__global__ __launch_bounds__(256) void k_norm(const float* __restrict__ drug1,
                                              const float* __restrict__ drug2,
                                              short* __restrict__ d1b,
                                              short* __restrict__ d2b,
                                              short* __restrict__ d1t,
                                              short* __restrict__ d2t) {
    __shared__ __attribute__((aligned(16))) short T[Dd * 64];   // 16 KB, swizzled
    const int tid = threadIdx.x;
    const int b = blockIdx.y;
    const int n0 = blockIdx.x * 64;
    const float* src; short* dstR; short* dstT;
    if (blockIdx.z == 0) { src = drug1; dstR = d1b; dstT = d1t; }
    else                 { src = drug2; dstR = d2b; dstT = d2t; }

    const int r64 = tid >> 2;        // row within tile (0..63)
    const int q4  = tid & 3;         // d-quarter (0..3)
    const int n = n0 + r64;
    const float* rp = src + ((long)b * Nn + n) * Dd + q4 * 32;
    float x[32];
    #pragma unroll
    for (int k = 0; k < 8; ++k) {
        const float4 v = *(const float4*)(rp + k * 4);
        x[k*4+0] = v.x; x[k*4+1] = v.y; x[k*4+2] = v.z; x[k*4+3] = v.w;
    }
    float ss = 0.f;
    #pragma unroll
    for (int e = 0; e < 32; ++e) ss += x[e] * x[e];
    ss += __shfl_xor(ss, 1, 64);     // lanes of a row are a contiguous quad
    ss += __shfl_xor(ss, 2, 64);
    const float inv = 1.0f / fmaxf(sqrtf(ss), 1e-12f);
    union { unsigned short us[32]; bf16x8 v8[4]; } o;
    #pragma unroll
    for (int e = 0; e < 32; ++e) o.us[e] = f2bf(x[e] * inv);
    short* wrp = dstR + ((long)b * Nn + n) * Dd + q4 * 32;
    #pragma unroll
    for (int k = 0; k < 4; ++k) *(bf16x8*)(wrp + k * 8) = o.v8[k];
    // transpose into LDS; column swizzle col^(8*q4) breaks the d-group conflict
    const int colp = r64 ^ (8 * q4);
    #pragma unroll
    for (int e = 0; e < 32; ++e) T[(q4 * 32 + e) * 64 + colp] = (short)o.us[e];
    __syncthreads();
    // coalesced b128 stores of Kt rows (undo swizzle: group gi read at gi^(d>>5))
    const int d = tid >> 1, h = tid & 1;
    short* wtp = dstT + ((long)b * Dd + d) * Nn + n0;
    #pragma unroll
    for (int k = 0; k < 4; ++k) {
        const int gi  = h * 4 + k;
        const int gip = gi ^ (d >> 5);
        *(bf16x8*)(wtp + gi * 8) = *(const bf16x8*)&T[d * 64 + gip * 8];
    }
}

// ---------------------------------------------------------------------------
// Kernel 2: dual-direction attention. NO LDS, NO barriers. Each wave: 32 Q rows.
// S' = K·Q^T (A=K rows, B=Q rows -> both contiguous); P redistributed to A-frag
// layout via 16 ds_bpermute; PV B-frags read from the global transposed copy.
__global__ __launch_bounds__(256) void k_attn(const short* __restrict__ d1b,
                                              const short* __restrict__ d2b,
                                              const short* __restrict__ d1t,
                                              const short* __restrict__ d2t,
                                              short* __restrict__ layerA,
                                              short* __restrict__ layerB) {
    const int tid = threadIdx.x, wave = tid >> 6, lane = tid & 63;
    const int m = lane & 15, g = lane >> 4;
    const short *Q, *K, *Kt; short* O;
    if (blockIdx.z == 0) { Q = d1b; K = d2b; Kt = d2t; O = layerA; }
    else                 { Q = d2b; K = d1b; Kt = d1t; O = layerB; }
    const int b = blockIdx.y;
    const int q0 = blockIdx.x * 128 + wave * 32;

    const short* Qb = Q + ((long)b * Nn + q0) * Dd;
    bf16x8 qf[2][4];                 // B-frags of Q (lane: Q[qt*16+m][c*32+g*8+j])
    #pragma unroll
    for (int qt = 0; qt < 2; ++qt)
        #pragma unroll
        for (int c = 0; c < 4; ++c)
            qf[qt][c] = *(const bf16x8*)(Qb + (qt * 16 + m) * Dd + c * 32 + g * 8);

    f32x4 oacc[2][8];
    #pragma unroll
    for (int qt = 0; qt < 2; ++qt)
        #pragma unroll
        for (int t = 0; t < 8; ++t) oacc[qt][t] = (f32x4){0.f, 0.f, 0.f, 0.f};
    float lsum[2] = {0.f, 0.f};

    const short* kp = K  + (long)b * Nn * Dd + m * Dd + g * 8;   // K row base
    const short* vp = Kt + (long)b * Dd * Nn + m * Nn + g * 8;   // Kt row base
    const int srcA = m + 32 * (g & 1);
    const bool glo = (g < 2);

    for (int it = 0; it < 32; ++it) {
        // ---- S' = K·Q^T : D[row=kv-in-tile=4g+r][col=q=m] ----
        f32x4 st[2][2];
        #pragma unroll
        for (int qt = 0; qt < 2; ++qt)
            #pragma unroll
            for (int kt = 0; kt < 2; ++kt) st[qt][kt] = (f32x4){0.f, 0.f, 0.f, 0.f};
        #pragma unroll
        for (int kt = 0; kt < 2; ++kt)
            #pragma unroll
            for (int c = 0; c < 4; ++c) {
                const bf16x8 kf = *(const bf16x8*)(kp + kt * 16 * Dd + c * 32);
                st[0][kt] = __builtin_amdgcn_mfma_f32_16x16x32_bf16(kf, qf[0][c], st[0][kt], 0, 0, 0);
                st[1][kt] = __builtin_amdgcn_mfma_f32_16x16x32_bf16(kf, qf[1][c], st[1][kt], 0, 0, 0);
            }
        // ---- V B-frags from global transposed copy (L2-resident) ----
        bf16x8 vf[8];
        #pragma unroll
        for (int t = 0; t < 8; ++t) vf[t] = *(const bf16x8*)(vp + t * 16 * Nn);

        #pragma unroll
        for (int qt = 0; qt < 2; ++qt) {
            // exp + pack to bf16 pairs: pk[kt][h] holds kv = 16kt+4g+{2h,2h+1}
            unsigned pk[2][2];
            #pragma unroll
            for (int kt = 0; kt < 2; ++kt) {
                const float e0 = exp2f(st[qt][kt][0] * CEXP);
                const float e1 = exp2f(st[qt][kt][1] * CEXP);
                const float e2 = exp2f(st[qt][kt][2] * CEXP);
                const float e3 = exp2f(st[qt][kt][3] * CEXP);
                pk[kt][0] = cvt_pk_bf16(e0, e1);
                pk[kt][1] = cvt_pk_bf16(e2, e3);
            }
            // bf16-consistent row-sum partials (q = m), reduced over g at end
            #pragma unroll
            for (int kt = 0; kt < 2; ++kt)
                #pragma unroll
                for (int hh = 0; hh < 2; ++hh) {
                    const unsigned u = pk[kt][hh];
                    lsum[qt] += __uint_as_float(u << 16) + __uint_as_float(u & 0xFFFF0000u);
                }
            // redistribute into A-frag: lane(m,g) needs P[q=m][kv=8g+j]
            const unsigned w0 = __shfl(pk[0][0], srcA, 64);
            const unsigned w1 = __shfl(pk[0][1], srcA, 64);
            const unsigned w2 = __shfl(pk[0][0], srcA + 16, 64);
            const unsigned w3 = __shfl(pk[0][1], srcA + 16, 64);
            const unsigned x0 = __shfl(pk[1][0], srcA, 64);
            const unsigned x1 = __shfl(pk[1][1], srcA, 64);
            const unsigned x2 = __shfl(pk[1][0], srcA + 16, 64);
            const unsigned x3 = __shfl(pk[1][1], srcA + 16, 64);
            union { unsigned u[4]; bf16x8 v; } af;
            af.u[0] = glo ? w0 : x0;
            af.u[1] = glo ? w1 : x1;
            af.u[2] = glo ? w2 : x2;
            af.u[3] = glo ? w3 : x3;
            // ---- O += P·V ----
            #pragma unroll
            for (int t = 0; t < 8; ++t)
                oacc[qt][t] = __builtin_amdgcn_mfma_f32_16x16x32_bf16(af.v, vf[t], oacc[qt][t], 0, 0, 0);
        }
        kp += 32 * Dd;
        vp += 32;
    }

    #pragma unroll
    for (int qt = 0; qt < 2; ++qt) {
        lsum[qt] += __shfl_xor(lsum[qt], 16, 64);
        lsum[qt] += __shfl_xor(lsum[qt], 32, 64);
    }
    short* ob = O + ((long)b * Nn + q0) * Dd;
    #pragma unroll
    for (int qt = 0; qt < 2; ++qt)
        #pragma unroll
        for (int r = 0; r < 4; ++r) {
            const float inv = 1.0f / __shfl(lsum[qt], 4 * g + r, 64);
            #pragma unroll
            for (int t = 0; t < 8; ++t)
                ob[(qt * 16 + 4 * g + r) * Dd + t * 16 + m] =
                    (short)f2bf(oacc[qt][t][r] * inv);
        }
}

// ---------------------------------------------------------------------------
// Kernel 3: fusion row -> fc1(256->64) + relu + softmax(64) ; pooled*w.
__global__ __launch_bounds__(256) void k_fuse(const float* __restrict__ drug1,
                                              const float* __restrict__ drug2,
                                              const short* __restrict__ layA,
                                              const short* __restrict__ layB,
                                              const float* __restrict__ fc1w,
                                              const float* __restrict__ fc1b,
                                              float* __restrict__ out) {
    __shared__ __attribute__((aligned(16))) short Wl[OUTW][260];
    __shared__ __attribute__((aligned(16))) float fus[4][256];
    const int tid = threadIdx.x, wave = tid >> 6, lane = tid & 63;

    for (int i = tid; i < OUTW * 256; i += 256)
        Wl[i >> 8][i & 255] = (short)f2bf(fc1w[i]);
    const float bias = fc1b[lane];
    __syncthreads();

    for (int rep = 0; rep < 16; ++rep) {
        const int row = blockIdx.x * 64 + wave * 16 + rep;
        const int bb = row >> 11;
        const int i  = row & 2047;
        const float* src; const short* lay; int n;
        if (i < Nn) { src = drug1; lay = layA; n = i; }
        else        { src = drug2; lay = layB; n = i - Nn; }
        const long base = ((long)bb * Nn + n) * Dd + lane * 2;
        const float2 v  = *(const float2*)(src + base);
        const short2 ls = *(const short2*)(lay + base);
        float ss = v.x * v.x + v.y * v.y;
        #pragma unroll
        for (int msk = 1; msk < 64; msk <<= 1) ss += __shfl_xor(ss, msk, 64);
        const float inv = 1.0f / fmaxf(sqrtf(ss), 1e-12f);
        fus[wave][lane * 2]           = v.x * inv;
        fus[wave][lane * 2 + 1]       = v.y * inv;
        fus[wave][128 + lane * 2]     = bf2f(ls.x);
        fus[wave][128 + lane * 2 + 1] = bf2f(ls.y);
        __syncthreads();
        float acc = bias;
        #pragma unroll 16
        for (int f4 = 0; f4 < 64; ++f4) {
            const float4 fv = *(const float4*)&fus[wave][f4 * 4];
            const bf16x4 wv = *(const bf16x4*)&Wl[lane][f4 * 4];
            acc += fv.x * bf2f(wv[0]) + fv.y * bf2f(wv[1])
                 + fv.z * bf2f(wv[2]) + fv.w * bf2f(wv[3]);
        }
        acc = fmaxf(acc, 0.0f);
        float mx = acc;
        #pragma unroll
        for (int msk = 1; msk < 64; msk <<= 1) mx = fmaxf(mx, __shfl_xor(mx, msk, 64));
        const float e = exp2f((acc - mx) * 1.4426950408889634f);
        float sum = e;
        #pragma unroll
        for (int msk = 1; msk < 64; msk <<= 1) sum += __shfl_xor(sum, msk, 64);
        const float w = e / sum;
        const float4 pv = *(const float4*)&fus[wave][lane * 4];
        const float pooled = 0.25f * (pv.x + pv.y + pv.z + pv.w);
        out[(long)row * OUTW + lane] = pooled * w;
        __syncthreads();
    }
}

// ---------------------------------------------------------------------------
extern "C" void kernel_launch(void* const* d_in, const int* in_sizes, int n_in,
                              void* d_out, int out_size, void* d_ws, size_t ws_size,
                              hipStream_t stream) {
    const float* drug1 = (const float*)d_in[0];
    const float* drug2 = (const float*)d_in[1];
    const float* fc1w  = (const float*)d_in[2];
    const float* fc1b  = (const float*)d_in[3];
    float* out = (float*)d_out;

    // workspace layout (48 MB, proven size from round 1)
    char* ws = (char*)d_ws;
    short* d1b    = (short*)(ws);                  //  8 MB bf16 d1 row-major
    short* d2b    = (short*)(ws + 8388608);        //  8 MB bf16 d2 row-major
    short* d1t    = (short*)(ws + 16777216);       //  8 MB bf16 d1 transposed [B][D][N]
    short* d2t    = (short*)(ws + 25165824);       //  8 MB bf16 d2 transposed
    short* layerA = (short*)(ws + 33554432);       //  8 MB bf16 drug2_layer
    short* layerB = (short*)(ws + 41943040);       //  8 MB bf16 drug1_layer

    hipLaunchKernelGGL(k_norm, dim3(16, 32, 2), dim3(256), 0, stream,
                       drug1, drug2, d1b, d2b, d1t, d2t);
    hipLaunchKernelGGL(k_attn, dim3(8, 32, 2), dim3(256), 0, stream,
                       d1b, d2b, d1t, d2t, layerA, layerB);
    hipLaunchKernelGGL(k_fuse, dim3(1024), dim3(256), 0, stream,
                       drug1, drug2, layerA, layerB, fc1w, fc1b, out);
}

// Round 3
// 242.047 us; speedup vs baseline: 1.3306x; 1.3242x over previous
//
#include <hip/hip_runtime.h>

#define Bz   32
#define Nn   1024
#define Dd   128
#define OUTW 64
#define CEXP 0.72134752044448169f   // 0.5 * log2(e)
#define LOG2E 1.4426950408889634f

typedef __attribute__((ext_vector_type(8))) short bf16x8;  // 8 bf16 = 4 VGPR
typedef __attribute__((ext_vector_type(4))) short bf16x4;
typedef __attribute__((ext_vector_type(4))) float f32x4;

static __device__ __forceinline__ unsigned short f2bf(float x) {
    unsigned u = __float_as_uint(x);
    u += 0x7FFFu + ((u >> 16) & 1u);            // RNE
    return (unsigned short)(u >> 16);
}
static __device__ __forceinline__ float bf2f(short b) {
    return __uint_as_float(((unsigned)(unsigned short)b) << 16);
}
static __device__ __forceinline__ unsigned cvt_pk_bf16(float lo, float hi) {
    unsigned r;
    asm("v_cvt_pk_bf16_f32 %0, %1, %2" : "=v"(r) : "v"(lo), "v"(hi));
    return r;
}

// ---------------------------------------------------------------------------
// Kernel 1: L2-normalize + emit bf16 row-major AND transposed [B][D][N] copies.
// LDS transpose with bijective XOR swizzle: conflict-free writes AND reads.
__global__ __launch_bounds__(256) void k_norm(const float* __restrict__ drug1,
                                              const float* __restrict__ drug2,
                                              short* __restrict__ d1b,
                                              short* __restrict__ d2b,
                                              short* __restrict__ d1t,
                                              short* __restrict__ d2t) {
    __shared__ __attribute__((aligned(16))) short T[Dd * 64];   // 16 KB
    const int tid = threadIdx.x;
    const int b = blockIdx.y;
    const int n0 = blockIdx.x * 64;
    const float* src; short* dstR; short* dstT;
    if (blockIdx.z == 0) { src = drug1; dstR = d1b; dstT = d1t; }
    else                 { src = drug2; dstR = d2b; dstT = d2t; }

    const int r64 = tid >> 2;        // row within tile (0..63)
    const int q4  = tid & 3;         // d-quarter (0..3)
    const int n = n0 + r64;
    const float* rp = src + ((long)b * Nn + n) * Dd + q4 * 32;
    float x[32];
    #pragma unroll
    for (int k = 0; k < 8; ++k) {
        const float4 v = *(const float4*)(rp + k * 4);
        x[k*4+0] = v.x; x[k*4+1] = v.y; x[k*4+2] = v.z; x[k*4+3] = v.w;
    }
    float ss = 0.f;
    #pragma unroll
    for (int e = 0; e < 32; ++e) ss += x[e] * x[e];
    ss += __shfl_xor(ss, 1, 64);
    ss += __shfl_xor(ss, 2, 64);
    const float inv = 1.0f / fmaxf(sqrtf(ss), 1e-12f);
    union { unsigned short us[32]; bf16x8 v8[4]; } o;
    #pragma unroll
    for (int e = 0; e < 32; ++e) o.us[e] = f2bf(x[e] * inv);
    short* wrp = dstR + ((long)b * Nn + n) * Dd + q4 * 32;
    #pragma unroll
    for (int k = 0; k < 4; ++k) *(bf16x8*)(wrp + k * 8) = o.v8[k];
    // transposed LDS write: d = q4*32+e, col = r64 ^ C(d)
    // C(d) = 16*(d>>5) ^ 8*((d>>2)&3) -> per-instruction disjoint bank sets
    #pragma unroll
    for (int e = 0; e < 32; ++e) {
        const int C = (16 * q4) ^ (8 * ((e >> 2) & 3));
        T[(q4 * 32 + e) * 64 + (r64 ^ C)] = (short)o.us[e];
    }
    __syncthreads();
    // b128 reads: group gi of 8 cols lives at physical base (8*gi)^C(d)
    const int d = tid >> 1, h = tid & 1;
    const int C = (16 * (d >> 5)) ^ (8 * ((d >> 2) & 3));
    short* wtp = dstT + ((long)b * Dd + d) * Nn + n0;
    #pragma unroll
    for (int k = 0; k < 4; ++k) {
        const int gi = h * 4 + k;
        *(bf16x8*)(wtp + gi * 8) = *(const bf16x8*)&T[d * 64 + ((gi * 8) ^ C)];
    }
}

// ---------------------------------------------------------------------------
// Kernel 2: dual-direction attention. No LDS, no barriers. 32 q-rows/wave.
// XCD-aware block remap + explicit register pipeline (K dbuf, V intra-iter).
__global__ __launch_bounds__(256, 2) void k_attn(const short* __restrict__ d1b,
                                                 const short* __restrict__ d2b,
                                                 const short* __restrict__ d1t,
                                                 const short* __restrict__ d2t,
                                                 short* __restrict__ layerA,
                                                 short* __restrict__ layerB) {
    // remap: all 8 q-blocks of one (b,z) share an XCD (bid%8 assumed rr->XCD)
    const int bid = blockIdx.x;            // 0..511
    const int xcd = bid & 7, tt = bid >> 3;
    const int jq = tt & 7, gq = tt >> 3;   // q-block, group-quarter
    const int grp = xcd + 8 * gq;          // 0..63 : (b, z)
    const int b = grp & 31, z = grp >> 5;

    const int tid = threadIdx.x, wave = tid >> 6, lane = tid & 63;
    const int m = lane & 15, g = lane >> 4;
    const short *Q, *K, *Kt; short* O;
    if (z == 0) { Q = d1b; K = d2b; Kt = d2t; O = layerA; }
    else        { Q = d2b; K = d1b; Kt = d1t; O = layerB; }
    const int q0 = jq * 128 + wave * 32;

    const short* Qb = Q + ((long)b * Nn + q0) * Dd;
    bf16x8 qf[2][4];                 // B-frags of Q
    #pragma unroll
    for (int qt = 0; qt < 2; ++qt)
        #pragma unroll
        for (int c = 0; c < 4; ++c)
            qf[qt][c] = *(const bf16x8*)(Qb + (qt * 16 + m) * Dd + c * 32 + g * 8);

    f32x4 oacc[2][8];
    #pragma unroll
    for (int qt = 0; qt < 2; ++qt)
        #pragma unroll
        for (int t = 0; t < 8; ++t) oacc[qt][t] = (f32x4){0.f, 0.f, 0.f, 0.f};
    float lsum[2] = {0.f, 0.f};

    const short* kp = K  + (long)b * Nn * Dd + m * Dd + g * 8;
    const short* vp = Kt + (long)b * Dd * Nn + m * Nn + g * 8;
    const int srcA = m + 32 * (g & 1);
    const bool glo = (g < 2);

    auto loadK = [&](int it, bf16x8* kf) {
        const short* p = kp + (long)it * 32 * Dd;
        #pragma unroll
        for (int kt = 0; kt < 2; ++kt)
            #pragma unroll
            for (int c = 0; c < 4; ++c)
                kf[kt * 4 + c] = *(const bf16x8*)(p + kt * 16 * Dd + c * 32);
    };

    auto step = [&](const bf16x8* kf, int it) {
        // V frags issued first: consumed only after QK + softmax (~self-hiding)
        bf16x8 vf[8];
        const short* pv = vp + it * 32;
        #pragma unroll
        for (int t = 0; t < 8; ++t) vf[t] = *(const bf16x8*)(pv + t * 16 * Nn);

        f32x4 st[2][2];
        #pragma unroll
        for (int qt = 0; qt < 2; ++qt)
            #pragma unroll
            for (int kt = 0; kt < 2; ++kt) st[qt][kt] = (f32x4){0.f, 0.f, 0.f, 0.f};
        __builtin_amdgcn_s_setprio(1);
        #pragma unroll
        for (int kt = 0; kt < 2; ++kt)
            #pragma unroll
            for (int c = 0; c < 4; ++c) {
                st[0][kt] = __builtin_amdgcn_mfma_f32_16x16x32_bf16(kf[kt*4+c], qf[0][c], st[0][kt], 0, 0, 0);
                st[1][kt] = __builtin_amdgcn_mfma_f32_16x16x32_bf16(kf[kt*4+c], qf[1][c], st[1][kt], 0, 0, 0);
            }
        __builtin_amdgcn_s_setprio(0);

        #pragma unroll
        for (int qt = 0; qt < 2; ++qt) {
            unsigned pk[2][2];
            #pragma unroll
            for (int kt = 0; kt < 2; ++kt) {
                const float e0 = exp2f(st[qt][kt][0] * CEXP);
                const float e1 = exp2f(st[qt][kt][1] * CEXP);
                const float e2 = exp2f(st[qt][kt][2] * CEXP);
                const float e3 = exp2f(st[qt][kt][3] * CEXP);
                pk[kt][0] = cvt_pk_bf16(e0, e1);
                pk[kt][1] = cvt_pk_bf16(e2, e3);
            }
            #pragma unroll
            for (int kt = 0; kt < 2; ++kt)
                #pragma unroll
                for (int hh = 0; hh < 2; ++hh) {
                    const unsigned u = pk[kt][hh];
                    lsum[qt] += __uint_as_float(u << 16) + __uint_as_float(u & 0xFFFF0000u);
                }
            const unsigned w0 = __shfl(pk[0][0], srcA, 64);
            const unsigned w1 = __shfl(pk[0][1], srcA, 64);
            const unsigned w2 = __shfl(pk[0][0], srcA + 16, 64);
            const unsigned w3 = __shfl(pk[0][1], srcA + 16, 64);
            const unsigned x0 = __shfl(pk[1][0], srcA, 64);
            const unsigned x1 = __shfl(pk[1][1], srcA, 64);
            const unsigned x2 = __shfl(pk[1][0], srcA + 16, 64);
            const unsigned x3 = __shfl(pk[1][1], srcA + 16, 64);
            union { unsigned u[4]; bf16x8 v; } af;
            af.u[0] = glo ? w0 : x0;
            af.u[1] = glo ? w1 : x1;
            af.u[2] = glo ? w2 : x2;
            af.u[3] = glo ? w3 : x3;
            __builtin_amdgcn_s_setprio(1);
            #pragma unroll
            for (int t = 0; t < 8; ++t)
                oacc[qt][t] = __builtin_amdgcn_mfma_f32_16x16x32_bf16(af.v, vf[t], oacc[qt][t], 0, 0, 0);
            __builtin_amdgcn_s_setprio(0);
        }
    };

    bf16x8 kfA[8], kfB[8];
    loadK(0, kfA);
    for (int it = 0; it < 32; it += 2) {
        loadK(it + 1, kfB);       // prefetch next K
        step(kfA, it);
        loadK(it + 2, kfA);       // it=30 -> overfetch into adjacent ws region (safe)
        step(kfB, it + 1);
    }

    #pragma unroll
    for (int qt = 0; qt < 2; ++qt) {
        lsum[qt] += __shfl_xor(lsum[qt], 16, 64);
        lsum[qt] += __shfl_xor(lsum[qt], 32, 64);
    }
    short* ob = O + ((long)b * Nn + q0) * Dd;
    #pragma unroll
    for (int qt = 0; qt < 2; ++qt)
        #pragma unroll
        for (int r = 0; r < 4; ++r) {
            const float inv = 1.0f / __shfl(lsum[qt], 4 * g + r, 64);
            #pragma unroll
            for (int t = 0; t < 8; ++t)
                ob[(qt * 16 + 4 * g + r) * Dd + t * 16 + m] =
                    (short)f2bf(oacc[qt][t][r] * inv);
        }
}

// ---------------------------------------------------------------------------
// Kernel 3: MFMA fc1 (bf16) + relu + softmax + pooled*w.  No LDS, no barriers.
// Block = 4 waves, each wave: 16 fusion rows per chunk, 2 chunks.
__global__ __launch_bounds__(256, 2) void k_fuse(const float* __restrict__ drug1,
                                                 const float* __restrict__ drug2,
                                                 const short* __restrict__ d1b,
                                                 const short* __restrict__ d2b,
                                                 const short* __restrict__ layA,
                                                 const short* __restrict__ layB,
                                                 const float* __restrict__ fc1w,
                                                 const float* __restrict__ fc1b,
                                                 float* __restrict__ out) {
    const int tid = threadIdx.x, wave = tid >> 6, lane = tid & 63;
    const int m = lane & 15, g = lane >> 4;

    // B-frags of W^T, built once: wb[t][c] = W[16t+m][32c+8g .. +8] as bf16
    bf16x8 wb[4][8];
    #pragma unroll
    for (int t = 0; t < 4; ++t)
        #pragma unroll
        for (int c = 0; c < 8; ++c) {
            const float* wp = fc1w + (t * 16 + m) * 256 + c * 32 + g * 8;
            const float4 a = *(const float4*)wp;
            const float4 bq = *(const float4*)(wp + 4);
            union { unsigned u[4]; bf16x8 v; } pk;
            pk.u[0] = cvt_pk_bf16(a.x, a.y);
            pk.u[1] = cvt_pk_bf16(a.z, a.w);
            pk.u[2] = cvt_pk_bf16(bq.x, bq.y);
            pk.u[3] = cvt_pk_bf16(bq.z, bq.w);
            wb[t][c] = pk.v;
        }
    float bias[4];
    #pragma unroll
    for (int t = 0; t < 4; ++t) bias[t] = fc1b[t * 16 + m];

    #pragma unroll
    for (int cc = 0; cc < 2; ++cc) {
        const int row0 = blockIdx.x * 128 + cc * 64 + wave * 16;  // 0..65535
        const int bb = row0 >> 11;
        const int i0 = row0 & 2047;
        const bool hf = (i0 >= Nn);
        const int ii = hf ? i0 - Nn : i0;
        const short* dsrc = (hf ? d2b : d1b) + ((long)bb * Nn + ii) * Dd;
        const short* lsrc = (hf ? layB : layA) + ((long)bb * Nn + ii) * Dd;
        const float* fsrc = (hf ? drug2 : drug1) + ((long)bb * Nn + ii) * Dd;

        f32x4 acc[4];
        #pragma unroll
        for (int t = 0; t < 4; ++t) acc[t] = (f32x4){0.f, 0.f, 0.f, 0.f};
        #pragma unroll
        for (int c = 0; c < 8; ++c) {
            const short* ap = (c < 4 ? dsrc + (long)m * Dd + c * 32
                                     : lsrc + (long)m * Dd + (c - 4) * 32) + g * 8;
            const bf16x8 af = *(const bf16x8*)ap;
            #pragma unroll
            for (int t = 0; t < 4; ++t)
                acc[t] = __builtin_amdgcn_mfma_f32_16x16x32_bf16(af, wb[t][c], acc[t], 0, 0, 0);
        }
        // epilogue: lane(m,g) holds rows rr=4g+r, channels 16t+m
        #pragma unroll
        for (int r = 0; r < 4; ++r) {
            float v[4];
            #pragma unroll
            for (int t = 0; t < 4; ++t) v[t] = fmaxf(acc[t][r] + bias[t], 0.f);
            float mx = fmaxf(fmaxf(v[0], v[1]), fmaxf(v[2], v[3]));
            #pragma unroll
            for (int msk = 1; msk < 16; msk <<= 1)
                mx = fmaxf(mx, __shfl_xor(mx, msk, 64));
            float e[4], sum = 0.f;
            #pragma unroll
            for (int t = 0; t < 4; ++t) { e[t] = exp2f((v[t] - mx) * LOG2E); sum += e[t]; }
            #pragma unroll
            for (int msk = 1; msk < 16; msk <<= 1) sum += __shfl_xor(sum, msk, 64);
            const float rinv = 1.0f / sum;

            const int rr = 4 * g + r;
            const float* fr = fsrc + (long)rr * Dd;
            const short* lr = lsrc + (long)rr * Dd;
            const float4 d0 = *(const float4*)(fr + 4 * m);
            const float4 d1 = *(const float4*)(fr + 64 + 4 * m);
            float ss = d0.x*d0.x + d0.y*d0.y + d0.z*d0.z + d0.w*d0.w
                     + d1.x*d1.x + d1.y*d1.y + d1.z*d1.z + d1.w*d1.w;
            #pragma unroll
            for (int msk = 1; msk < 16; msk <<= 1) ss += __shfl_xor(ss, msk, 64);
            const float ninv = 1.0f / fmaxf(sqrtf(ss), 1e-12f);
            const short4 l0 = *(const short4*)(lr + 4 * m);
            const short4 l1 = *(const short4*)(lr + 64 + 4 * m);
            float pooled[4];
            pooled[0] = 0.25f * (d0.x + d0.y + d0.z + d0.w) * ninv;
            pooled[1] = 0.25f * (d1.x + d1.y + d1.z + d1.w) * ninv;
            pooled[2] = 0.25f * (bf2f(l0.x) + bf2f(l0.y) + bf2f(l0.z) + bf2f(l0.w));
            pooled[3] = 0.25f * (bf2f(l1.x) + bf2f(l1.y) + bf2f(l1.z) + bf2f(l1.w));
            float* op = out + ((long)row0 + rr) * OUTW;
            #pragma unroll
            for (int t = 0; t < 4; ++t) op[t * 16 + m] = pooled[t] * (e[t] * rinv);
        }
    }
}

// ---------------------------------------------------------------------------
extern "C" void kernel_launch(void* const* d_in, const int* in_sizes, int n_in,
                              void* d_out, int out_size, void* d_ws, size_t ws_size,
                              hipStream_t stream) {
    const float* drug1 = (const float*)d_in[0];
    const float* drug2 = (const float*)d_in[1];
    const float* fc1w  = (const float*)d_in[2];
    const float* fc1b  = (const float*)d_in[3];
    float* out = (float*)d_out;

    char* ws = (char*)d_ws;                        // 48 MB total (proven)
    short* d1b    = (short*)(ws);                  //  8 MB bf16 d1 row-major
    short* d2b    = (short*)(ws + 8388608);        //  8 MB bf16 d2 row-major
    short* d1t    = (short*)(ws + 16777216);       //  8 MB bf16 d1 transposed
    short* d2t    = (short*)(ws + 25165824);       //  8 MB bf16 d2 transposed
    short* layerA = (short*)(ws + 33554432);       //  8 MB bf16 drug2_layer
    short* layerB = (short*)(ws + 41943040);       //  8 MB bf16 drug1_layer

    hipLaunchKernelGGL(k_norm, dim3(16, 32, 2), dim3(256), 0, stream,
                       drug1, drug2, d1b, d2b, d1t, d2t);
    hipLaunchKernelGGL(k_attn, dim3(512), dim3(256), 0, stream,
                       d1b, d2b, d1t, d2t, layerA, layerB);
    hipLaunchKernelGGL(k_fuse, dim3(512), dim3(256), 0, stream,
                       drug1, drug2, d1b, d2b, layerA, layerB, fc1w, fc1b, out);
}

// Round 5
// 239.187 us; speedup vs baseline: 1.3465x; 1.0120x over previous
//
#include <hip/hip_runtime.h>

#define Bz   32
#define Nn   1024
#define Dd   128
#define OUTW 64
#define CEXP 0.72134752044448169f   // 0.5 * log2(e)
#define LOG2E 1.4426950408889634f

typedef __attribute__((ext_vector_type(8))) short bf16x8;  // 8 bf16 = 4 VGPR
typedef __attribute__((ext_vector_type(4))) short bf16x4;
typedef __attribute__((ext_vector_type(4))) float f32x4;

static __device__ __forceinline__ unsigned short f2bf(float x) {
    unsigned u = __float_as_uint(x);
    u += 0x7FFFu + ((u >> 16) & 1u);            // RNE
    return (unsigned short)(u >> 16);
}
static __device__ __forceinline__ float bf2f(short b) {
    return __uint_as_float(((unsigned)(unsigned short)b) << 16);
}
static __device__ __forceinline__ unsigned cvt_pk_bf16(float lo, float hi) {
    unsigned r;
    asm("v_cvt_pk_bf16_f32 %0, %1, %2" : "=v"(r) : "v"(lo), "v"(hi));
    return r;
}
// opaque global load: compiler cannot sink it to the use site
static __device__ __forceinline__ bf16x8 gload16(const short* p) {
    bf16x8 r;
    asm volatile("global_load_dwordx4 %0, %1, off" : "=v"(r) : "v"(p) : "memory");
    return r;
}
#define WAITV(n) { asm volatile("s_waitcnt vmcnt(" #n ")" ::: "memory"); \
                   __builtin_amdgcn_sched_barrier(0); }

// ---------------------------------------------------------------------------
// Kernel 1: L2-normalize + bf16 row-major AND transposed [B][D][N] copies.
// Coalesced: lane owns one contiguous float4; wave covers 2 rows per instr.
__global__ __launch_bounds__(256) void k_norm(const float* __restrict__ drug1,
                                              const float* __restrict__ drug2,
                                              short* __restrict__ d1b,
                                              short* __restrict__ d2b,
                                              short* __restrict__ d1t,
                                              short* __restrict__ d2t) {
    __shared__ __attribute__((aligned(16))) short T[Dd * 64];   // 16 KB
    const int tid = threadIdx.x, wave = tid >> 6, lane = tid & 63;
    const int b = blockIdx.y;
    const int n0 = blockIdx.x * 64;
    const float* src; short* dstR; short* dstT;
    if (blockIdx.z == 0) { src = drug1; dstR = d1b; dstT = d1t; }
    else                 { src = drug2; dstR = d2b; dstT = d2t; }

    const int rh = lane >> 5;          // 0/1: which row of the pair
    const int c  = lane & 31;          // float4 chunk within the row
    #pragma unroll
    for (int i = 0; i < 8; ++i) {
        const int col = wave * 16 + i * 2 + rh;       // 0..63 tile row
        const int n = n0 + col;
        const float4 v = *(const float4*)(src + ((long)b * Nn + n) * Dd + c * 4);
        float ss = v.x * v.x + v.y * v.y + v.z * v.z + v.w * v.w;
        #pragma unroll
        for (int msk = 1; msk < 32; msk <<= 1) ss += __shfl_xor(ss, msk, 64);
        const float inv = 1.0f / fmaxf(sqrtf(ss), 1e-12f);
        const unsigned p0 = cvt_pk_bf16(v.x * inv, v.y * inv);
        const unsigned p1 = cvt_pk_bf16(v.z * inv, v.w * inv);
        // row-major bf16 write: 8B/lane, contiguous across the wave
        uint2 u2; u2.x = p0; u2.y = p1;
        *(uint2*)(dstR + ((long)b * Nn + n) * Dd + c * 4) = u2;
        // transposed LDS fill, swizzled col ^= C(d); <=2-way conflicts
        const unsigned short e0 = (unsigned short)(p0 & 0xFFFF);
        const unsigned short e1 = (unsigned short)(p0 >> 16);
        const unsigned short e2 = (unsigned short)(p1 & 0xFFFF);
        const unsigned short e3 = (unsigned short)(p1 >> 16);
        const int Csw = (16 * (c >> 3)) ^ (8 * (c & 3));
        const int pc = col ^ Csw;
        T[(c * 4 + 0) * 64 + pc] = (short)e0;
        T[(c * 4 + 1) * 64 + pc] = (short)e1;
        T[(c * 4 + 2) * 64 + pc] = (short)e2;
        T[(c * 4 + 3) * 64 + pc] = (short)e3;
    }
    __syncthreads();
    // b128 reads of transposed rows (proven round-3 path)
    const int d = tid >> 1, h = tid & 1;
    const int C = (16 * (d >> 5)) ^ (8 * ((d >> 2) & 3));
    short* wtp = dstT + ((long)b * Dd + d) * Nn + n0;
    #pragma unroll
    for (int k = 0; k < 4; ++k) {
        const int gi = h * 4 + k;
        *(bf16x8*)(wtp + gi * 8) = *(const bf16x8*)&T[d * 64 + ((gi * 8) ^ C)];
    }
}

// ---------------------------------------------------------------------------
// Kernel 2: dual-direction attention. No LDS/barriers. 32 q-rows/wave.
// Inline-asm loads + counted vmcnt: K double-buffered, V issued-early.
// Row sums via ones-column MFMA (no VALU unpack, no epilogue shuffles).
__global__ __launch_bounds__(256, 2) void k_attn(const short* __restrict__ d1b,
                                                 const short* __restrict__ d2b,
                                                 const short* __restrict__ d1t,
                                                 const short* __restrict__ d2t,
                                                 short* __restrict__ layerA,
                                                 short* __restrict__ layerB) {
    const int bid = blockIdx.x;            // XCD-aware remap (round-3 proven)
    const int xcd = bid & 7, tt = bid >> 3;
    const int jq = tt & 7, gq = tt >> 3;
    const int grp = xcd + 8 * gq;          // (b, z)
    const int b = grp & 31, z = grp >> 5;

    const int tid = threadIdx.x, wave = tid >> 6, lane = tid & 63;
    const int m = lane & 15, g = lane >> 4;
    const short *Q, *K, *Kt; short* O;
    if (z == 0) { Q = d1b; K = d2b; Kt = d2t; O = layerA; }
    else        { Q = d2b; K = d1b; Kt = d1t; O = layerB; }
    const int q0 = jq * 128 + wave * 32;

    const short* Qb = Q + ((long)b * Nn + q0) * Dd;
    bf16x8 qf[2][4];
    #pragma unroll
    for (int qt = 0; qt < 2; ++qt)
        #pragma unroll
        for (int c = 0; c < 4; ++c)
            qf[qt][c] = *(const bf16x8*)(Qb + (qt * 16 + m) * Dd + c * 32 + g * 8);

    f32x4 oacc[2][8];
    f32x4 acc_l[2];
    #pragma unroll
    for (int qt = 0; qt < 2; ++qt) {
        acc_l[qt] = (f32x4){0.f, 0.f, 0.f, 0.f};
        #pragma unroll
        for (int t = 0; t < 8; ++t) oacc[qt][t] = (f32x4){0.f, 0.f, 0.f, 0.f};
    }
    bf16x8 ones;
    #pragma unroll
    for (int j = 0; j < 8; ++j) ones[j] = (short)0x3F80;   // bf16 1.0

    const short* kp = K  + (long)b * Nn * Dd + m * Dd + g * 8;
    const short* vp = Kt + (long)b * Dd * Nn + m * Nn + g * 8;
    const int srcA = m + 32 * (g & 1);
    const bool glo = (g < 2);

#define KLOAD(buf, it) { \
    _Pragma("unroll") for (int kt = 0; kt < 2; ++kt) \
    _Pragma("unroll") for (int cc = 0; cc < 4; ++cc) \
        buf[kt * 4 + cc] = gload16(kp + (long)(it) * 4096 + kt * 2048 + cc * 32); }
#define VLOAD(buf, it) { \
    _Pragma("unroll") for (int t = 0; t < 8; ++t) \
        buf[t] = gload16(vp + (it) * 32 + t * 16 * Nn); }

#define HALFSTEP(KBUF) { \
    f32x4 st[2][2]; \
    _Pragma("unroll") for (int qt = 0; qt < 2; ++qt) \
    _Pragma("unroll") for (int kt = 0; kt < 2; ++kt) \
        st[qt][kt] = (f32x4){0.f, 0.f, 0.f, 0.f}; \
    __builtin_amdgcn_s_setprio(1); \
    _Pragma("unroll") for (int kt = 0; kt < 2; ++kt) \
    _Pragma("unroll") for (int cc = 0; cc < 4; ++cc) { \
        st[0][kt] = __builtin_amdgcn_mfma_f32_16x16x32_bf16(KBUF[kt*4+cc], qf[0][cc], st[0][kt], 0, 0, 0); \
        st[1][kt] = __builtin_amdgcn_mfma_f32_16x16x32_bf16(KBUF[kt*4+cc], qf[1][cc], st[1][kt], 0, 0, 0); \
    } \
    __builtin_amdgcn_s_setprio(0); \
    unsigned afu[2][4]; \
    _Pragma("unroll") for (int qt = 0; qt < 2; ++qt) { \
        unsigned pk[2][2]; \
        _Pragma("unroll") for (int kt = 0; kt < 2; ++kt) { \
            const float e0 = exp2f(st[qt][kt][0] * CEXP); \
            const float e1 = exp2f(st[qt][kt][1] * CEXP); \
            const float e2 = exp2f(st[qt][kt][2] * CEXP); \
            const float e3 = exp2f(st[qt][kt][3] * CEXP); \
            pk[kt][0] = cvt_pk_bf16(e0, e1); \
            pk[kt][1] = cvt_pk_bf16(e2, e3); \
        } \
        const unsigned w0 = __shfl(pk[0][0], srcA, 64); \
        const unsigned w1 = __shfl(pk[0][1], srcA, 64); \
        const unsigned w2 = __shfl(pk[0][0], srcA + 16, 64); \
        const unsigned w3 = __shfl(pk[0][1], srcA + 16, 64); \
        const unsigned x0 = __shfl(pk[1][0], srcA, 64); \
        const unsigned x1 = __shfl(pk[1][1], srcA, 64); \
        const unsigned x2 = __shfl(pk[1][0], srcA + 16, 64); \
        const unsigned x3 = __shfl(pk[1][1], srcA + 16, 64); \
        afu[qt][0] = glo ? w0 : x0; \
        afu[qt][1] = glo ? w1 : x1; \
        afu[qt][2] = glo ? w2 : x2; \
        afu[qt][3] = glo ? w3 : x3; \
    } \
    WAITV(8); \
    __builtin_amdgcn_s_setprio(1); \
    _Pragma("unroll") for (int qt = 0; qt < 2; ++qt) { \
        union { unsigned u[4]; bf16x8 v; } af; \
        af.u[0] = afu[qt][0]; af.u[1] = afu[qt][1]; \
        af.u[2] = afu[qt][2]; af.u[3] = afu[qt][3]; \
        _Pragma("unroll") for (int t = 0; t < 8; ++t) \
            oacc[qt][t] = __builtin_amdgcn_mfma_f32_16x16x32_bf16(af.v, vf[t], oacc[qt][t], 0, 0, 0); \
        acc_l[qt] = __builtin_amdgcn_mfma_f32_16x16x32_bf16(af.v, ones, acc_l[qt], 0, 0, 0); \
    } \
    __builtin_amdgcn_s_setprio(0); }

    bf16x8 kfA[8], kfB[8], vf[8];
    KLOAD(kfA, 0);
    for (int it = 0; it < 32; it += 2) {
        VLOAD(vf, it);
        KLOAD(kfB, it + 1);
        WAITV(16);                 // K(it) ready; V+K(it+1) stay in flight
        HALFSTEP(kfA);
        VLOAD(vf, it + 1);
        KLOAD(kfA, it + 2);        // it=30: overfetch into adjacent ws (safe)
        WAITV(16);                 // K(it+1) ready
        HALFSTEP(kfB);
    }

    short* ob = O + ((long)b * Nn + q0) * Dd;
    #pragma unroll
    for (int qt = 0; qt < 2; ++qt)
        #pragma unroll
        for (int r = 0; r < 4; ++r) {
            const float inv = 1.0f / acc_l[qt][r];
            #pragma unroll
            for (int t = 0; t < 8; ++t)
                ob[(qt * 16 + 4 * g + r) * Dd + t * 16 + m] =
                    (short)f2bf(oacc[qt][t][r] * inv);
        }
#undef KLOAD
#undef VLOAD
#undef HALFSTEP
}

// ---------------------------------------------------------------------------
// Kernel 3: MFMA fc1 (bf16) + relu + softmax + pooled*w. (round-3 proven)
__global__ __launch_bounds__(256, 2) void k_fuse(const float* __restrict__ drug1,
                                                 const float* __restrict__ drug2,
                                                 const short* __restrict__ d1b,
                                                 const short* __restrict__ d2b,
                                                 const short* __restrict__ layA,
                                                 const short* __restrict__ layB,
                                                 const float* __restrict__ fc1w,
                                                 const float* __restrict__ fc1b,
                                                 float* __restrict__ out) {
    const int tid = threadIdx.x, wave = tid >> 6, lane = tid & 63;
    const int m = lane & 15, g = lane >> 4;

    bf16x8 wb[4][8];
    #pragma unroll
    for (int t = 0; t < 4; ++t)
        #pragma unroll
        for (int c = 0; c < 8; ++c) {
            const float* wp = fc1w + (t * 16 + m) * 256 + c * 32 + g * 8;
            const float4 a = *(const float4*)wp;
            const float4 bq = *(const float4*)(wp + 4);
            union { unsigned u[4]; bf16x8 v; } pk;
            pk.u[0] = cvt_pk_bf16(a.x, a.y);
            pk.u[1] = cvt_pk_bf16(a.z, a.w);
            pk.u[2] = cvt_pk_bf16(bq.x, bq.y);
            pk.u[3] = cvt_pk_bf16(bq.z, bq.w);
            wb[t][c] = pk.v;
        }
    float bias[4];
    #pragma unroll
    for (int t = 0; t < 4; ++t) bias[t] = fc1b[t * 16 + m];

    #pragma unroll
    for (int cc = 0; cc < 2; ++cc) {
        const int row0 = blockIdx.x * 128 + cc * 64 + wave * 16;
        const int bb = row0 >> 11;
        const int i0 = row0 & 2047;
        const bool hf = (i0 >= Nn);
        const int ii = hf ? i0 - Nn : i0;
        const short* dsrc = (hf ? d2b : d1b) + ((long)bb * Nn + ii) * Dd;
        const short* lsrc = (hf ? layB : layA) + ((long)bb * Nn + ii) * Dd;
        const float* fsrc = (hf ? drug2 : drug1) + ((long)bb * Nn + ii) * Dd;

        f32x4 acc[4];
        #pragma unroll
        for (int t = 0; t < 4; ++t) acc[t] = (f32x4){0.f, 0.f, 0.f, 0.f};
        #pragma unroll
        for (int c = 0; c < 8; ++c) {
            const short* ap = (c < 4 ? dsrc + (long)m * Dd + c * 32
                                     : lsrc + (long)m * Dd + (c - 4) * 32) + g * 8;
            const bf16x8 af = *(const bf16x8*)ap;
            #pragma unroll
            for (int t = 0; t < 4; ++t)
                acc[t] = __builtin_amdgcn_mfma_f32_16x16x32_bf16(af, wb[t][c], acc[t], 0, 0, 0);
        }
        #pragma unroll
        for (int r = 0; r < 4; ++r) {
            float v[4];
            #pragma unroll
            for (int t = 0; t < 4; ++t) v[t] = fmaxf(acc[t][r] + bias[t], 0.f);
            float mx = fmaxf(fmaxf(v[0], v[1]), fmaxf(v[2], v[3]));
            #pragma unroll
            for (int msk = 1; msk < 16; msk <<= 1)
                mx = fmaxf(mx, __shfl_xor(mx, msk, 64));
            float e[4], sum = 0.f;
            #pragma unroll
            for (int t = 0; t < 4; ++t) { e[t] = exp2f((v[t] - mx) * LOG2E); sum += e[t]; }
            #pragma unroll
            for (int msk = 1; msk < 16; msk <<= 1) sum += __shfl_xor(sum, msk, 64);
            const float rinv = 1.0f / sum;

            const int rr = 4 * g + r;
            const float* fr = fsrc + (long)rr * Dd;
            const short* lr = lsrc + (long)rr * Dd;
            const float4 d0 = *(const float4*)(fr + 4 * m);
            const float4 d1 = *(const float4*)(fr + 64 + 4 * m);
            float ss = d0.x*d0.x + d0.y*d0.y + d0.z*d0.z + d0.w*d0.w
                     + d1.x*d1.x + d1.y*d1.y + d1.z*d1.z + d1.w*d1.w;
            #pragma unroll
            for (int msk = 1; msk < 16; msk <<= 1) ss += __shfl_xor(ss, msk, 64);
            const float ninv = 1.0f / fmaxf(sqrtf(ss), 1e-12f);
            const short4 l0 = *(const short4*)(lr + 4 * m);
            const short4 l1 = *(const short4*)(lr + 64 + 4 * m);
            float pooled[4];
            pooled[0] = 0.25f * (d0.x + d0.y + d0.z + d0.w) * ninv;
            pooled[1] = 0.25f * (d1.x + d1.y + d1.z + d1.w) * ninv;
            pooled[2] = 0.25f * (bf2f(l0.x) + bf2f(l0.y) + bf2f(l0.z) + bf2f(l0.w));
            pooled[3] = 0.25f * (bf2f(l1.x) + bf2f(l1.y) + bf2f(l1.z) + bf2f(l1.w));
            float* op = out + ((long)row0 + rr) * OUTW;
            #pragma unroll
            for (int t = 0; t < 4; ++t) op[t * 16 + m] = pooled[t] * (e[t] * rinv);
        }
    }
}

// ---------------------------------------------------------------------------
extern "C" void kernel_launch(void* const* d_in, const int* in_sizes, int n_in,
                              void* d_out, int out_size, void* d_ws, size_t ws_size,
                              hipStream_t stream) {
    const float* drug1 = (const float*)d_in[0];
    const float* drug2 = (const float*)d_in[1];
    const float* fc1w  = (const float*)d_in[2];
    const float* fc1b  = (const float*)d_in[3];
    float* out = (float*)d_out;

    char* ws = (char*)d_ws;                        // 48 MB total (proven)
    short* d1b    = (short*)(ws);                  //  8 MB bf16 d1 row-major
    short* d2b    = (short*)(ws + 8388608);        //  8 MB bf16 d2 row-major
    short* d1t    = (short*)(ws + 16777216);       //  8 MB bf16 d1 transposed
    short* d2t    = (short*)(ws + 25165824);       //  8 MB bf16 d2 transposed
    short* layerA = (short*)(ws + 33554432);       //  8 MB bf16 drug2_layer
    short* layerB = (short*)(ws + 41943040);       //  8 MB bf16 drug1_layer

    hipLaunchKernelGGL(k_norm, dim3(16, 32, 2), dim3(256), 0, stream,
                       drug1, drug2, d1b, d2b, d1t, d2t);
    hipLaunchKernelGGL(k_attn, dim3(512), dim3(256), 0, stream,
                       d1b, d2b, d1t, d2t, layerA, layerB);
    hipLaunchKernelGGL(k_fuse, dim3(512), dim3(256), 0, stream,
                       drug1, drug2, d1b, d2b, layerA, layerB, fc1w, fc1b, out);
}

// Round 6
// 168.144 us; speedup vs baseline: 1.9154x; 1.4225x over previous
//
#include <hip/hip_runtime.h>

#define Bz   32
#define Nn   1024
#define Dd   128
#define OUTW 64
#define CEXP 0.72134752044448169f   // 0.5 * log2(e)
#define LOG2E 1.4426950408889634f

typedef __attribute__((ext_vector_type(8))) short bf16x8;  // 8 bf16 = 4 VGPR
typedef __attribute__((ext_vector_type(4))) short bf16x4;
typedef __attribute__((ext_vector_type(4))) float f32x4;

static __device__ __forceinline__ unsigned short f2bf(float x) {
    unsigned u = __float_as_uint(x);
    u += 0x7FFFu + ((u >> 16) & 1u);            // RNE
    return (unsigned short)(u >> 16);
}
static __device__ __forceinline__ float bf2f(short b) {
    return __uint_as_float(((unsigned)(unsigned short)b) << 16);
}
static __device__ __forceinline__ unsigned cvt_pk_bf16(float lo, float hi) {
    unsigned r;
    asm("v_cvt_pk_bf16_f32 %0, %1, %2" : "=v"(r) : "v"(lo), "v"(hi));
    return r;
}
// async global->LDS, 16B per lane; LDS dest = wave-uniform base + lane*16
#define GLL16(g, l) __builtin_amdgcn_global_load_lds( \
    (const __attribute__((address_space(1))) unsigned*)(const void*)(g), \
    (__attribute__((address_space(3))) unsigned*)(void*)(l), 16, 0, 0)
#define WAITVN(n) { asm volatile("s_waitcnt vmcnt(" #n ")" ::: "memory"); \
                    __builtin_amdgcn_sched_barrier(0); }
#define SBAR() __builtin_amdgcn_s_barrier()

// Global bf16 arrays carry a T2 swizzle: element [n][d] stored at
// [n][d ^ ((n&7)*8)]  (row-major)  /  [d][kv ^ ((d&7)*8)] within each
// 64-aligned kv window (transposed). XOR acts on bits>=3 -> 16B chunks map
// to 16B chunks, so vector loads/stores stay aligned and ds_read_b128 of a
// 16-row column slice spreads across all bank quads (conflict-free).

// ---------------------------------------------------------------------------
// Kernel 1: L2-normalize + swizzled bf16 row-major AND transposed copies.
__global__ __launch_bounds__(256) void k_norm(const float* __restrict__ drug1,
                                              const float* __restrict__ drug2,
                                              short* __restrict__ d1s,
                                              short* __restrict__ d2s,
                                              short* __restrict__ d1ts,
                                              short* __restrict__ d2ts) {
    __shared__ __attribute__((aligned(16))) short T[Dd * 64];   // 16 KB
    const int tid = threadIdx.x, wave = tid >> 6, lane = tid & 63;
    const int b = blockIdx.y;
    const int n0 = blockIdx.x * 64;
    const float* src; short* dstR; short* dstT;
    if (blockIdx.z == 0) { src = drug1; dstR = d1s; dstT = d1ts; }
    else                 { src = drug2; dstR = d2s; dstT = d2ts; }

    const int rh = lane >> 5;          // 0/1: which row of the pair
    const int c  = lane & 31;          // float4 chunk within the row
    #pragma unroll
    for (int i = 0; i < 8; ++i) {
        const int col = wave * 16 + i * 2 + rh;       // 0..63 tile row
        const int n = n0 + col;
        const float4 v = *(const float4*)(src + ((long)b * Nn + n) * Dd + c * 4);
        float ss = v.x * v.x + v.y * v.y + v.z * v.z + v.w * v.w;
        #pragma unroll
        for (int msk = 1; msk < 32; msk <<= 1) ss += __shfl_xor(ss, msk, 64);
        const float inv = 1.0f / fmaxf(sqrtf(ss), 1e-12f);
        const unsigned p0 = cvt_pk_bf16(v.x * inv, v.y * inv);
        const unsigned p1 = cvt_pk_bf16(v.z * inv, v.w * inv);
        // swizzled row-major write (8B, stays 8B-aligned under the XOR)
        uint2 u2; u2.x = p0; u2.y = p1;
        *(uint2*)(dstR + ((long)b * Nn + n) * Dd + ((c * 4) ^ ((n & 7) * 8))) = u2;
        // transposed LDS fill (internal swizzle, <=2-way conflicts)
        const unsigned short e0 = (unsigned short)(p0 & 0xFFFF);
        const unsigned short e1 = (unsigned short)(p0 >> 16);
        const unsigned short e2 = (unsigned short)(p1 & 0xFFFF);
        const unsigned short e3 = (unsigned short)(p1 >> 16);
        const int Csw = (16 * (c >> 3)) ^ (8 * (c & 3));
        const int pc = col ^ Csw;
        T[(c * 4 + 0) * 64 + pc] = (short)e0;
        T[(c * 4 + 1) * 64 + pc] = (short)e1;
        T[(c * 4 + 2) * 64 + pc] = (short)e2;
        T[(c * 4 + 3) * 64 + pc] = (short)e3;
    }
    __syncthreads();
    // b128 reads of transposed rows; global store at swizzled group gi^(d&7)
    const int d = tid >> 1, h = tid & 1;
    const int C = (16 * (d >> 5)) ^ (8 * ((d >> 2) & 3));
    short* wtp = dstT + ((long)b * Dd + d) * Nn + n0;
    #pragma unroll
    for (int k = 0; k < 4; ++k) {
        const int gi = h * 4 + k;
        *(bf16x8*)(wtp + ((gi ^ (d & 7)) * 8)) =
            *(const bf16x8*)&T[d * 64 + ((gi * 8) ^ C)];
    }
}

// ---------------------------------------------------------------------------
// Kernel 2: dual-direction attention, LDS-cooperative (m97 structure).
// Block = 4 waves, 128 q-rows; KV tile = 64, double-buffered in LDS via
// global_load_lds; counted vmcnt(8) keeps next tile in flight across barriers.
__global__ __launch_bounds__(256, 2) void k_attn(const short* __restrict__ d1s,
                                                 const short* __restrict__ d2s,
                                                 const short* __restrict__ d1ts,
                                                 const short* __restrict__ d2ts,
                                                 short* __restrict__ layerA,
                                                 short* __restrict__ layerB) {
    __shared__ __attribute__((aligned(16))) short Kl[2][64][128];  // 32 KB
    __shared__ __attribute__((aligned(16))) short Vl[2][128][64];  // 32 KB

    const int bid = blockIdx.x;            // XCD-aware remap (proven r3)
    const int xcd = bid & 7, tt = bid >> 3;
    const int jq = tt & 7, gq = tt >> 3;
    const int grp = xcd + 8 * gq;          // (b, z)
    const int b = grp & 31, z = grp >> 5;

    const int tid = threadIdx.x, wave = tid >> 6, lane = tid & 63;
    const int m = lane & 15, g = lane >> 4;
    const short *Q, *Ks, *Vts; short* O;
    if (z == 0) { Q = d1s; Ks = d2s; Vts = d2ts; O = layerA; }
    else        { Q = d2s; Ks = d1s; Vts = d1ts; O = layerB; }
    const int q0 = jq * 128 + wave * 32;
    const int sw = (m & 7) * 8;            // column swizzle for this lane

    // Q B-frags from swizzled rows
    const short* Qb = Q + ((long)b * Nn + q0) * Dd;
    bf16x8 qf[2][4];
    #pragma unroll
    for (int qt = 0; qt < 2; ++qt)
        #pragma unroll
        for (int c = 0; c < 4; ++c)
            qf[qt][c] = *(const bf16x8*)(Qb + (qt * 16 + m) * Dd
                                            + ((c * 32 + g * 8) ^ sw));

    f32x4 oacc[2][8];
    f32x4 acc_l[2];
    #pragma unroll
    for (int qt = 0; qt < 2; ++qt) {
        acc_l[qt] = (f32x4){0.f, 0.f, 0.f, 0.f};
        #pragma unroll
        for (int t = 0; t < 8; ++t) oacc[qt][t] = (f32x4){0.f, 0.f, 0.f, 0.f};
    }
    bf16x8 ones;
    #pragma unroll
    for (int j = 0; j < 8; ++j) ones[j] = (short)0x3F80;   // bf16 1.0

    const short* Ksb = Ks  + (long)b * Nn * Dd;
    const short* Vtb = Vts + (long)b * Dd * Nn;
    const int klr = lane >> 4, klc = lane & 15;   // K staging: 4 rows/instr
    const int vlr = lane >> 3, vlc = lane & 7;    // V staging: 8 rows/instr
    const int srcA = m + 32 * (g & 1);
    const bool glo = (g < 2);

    auto STAGE = [&](int buf, int tile) {
        const int kv0 = tile * 64;
        #pragma unroll
        for (int j = 0; j < 4; ++j)
            GLL16(Ksb + ((long)(kv0 + wave * 16 + j * 4 + klr)) * Dd + klc * 8,
                  &Kl[buf][wave * 16 + j * 4][0]);
        #pragma unroll
        for (int j = 0; j < 4; ++j)
            GLL16(Vtb + ((long)(wave * 32 + j * 8 + vlr)) * Nn + kv0 + vlc * 8,
                  &Vl[buf][wave * 32 + j * 8][0]);
    };

    auto HALF = [&](int buf, int kvsub) {
        f32x4 st[2][2];
        #pragma unroll
        for (int qt = 0; qt < 2; ++qt)
            #pragma unroll
            for (int kt = 0; kt < 2; ++kt) st[qt][kt] = (f32x4){0.f, 0.f, 0.f, 0.f};
        __builtin_amdgcn_s_setprio(1);
        #pragma unroll
        for (int kt = 0; kt < 2; ++kt)
            #pragma unroll
            for (int c = 0; c < 4; ++c) {
                const bf16x8 kf = *(const bf16x8*)
                    &Kl[buf][kvsub + kt * 16 + m][(c * 32 + g * 8) ^ sw];
                st[0][kt] = __builtin_amdgcn_mfma_f32_16x16x32_bf16(kf, qf[0][c], st[0][kt], 0, 0, 0);
                st[1][kt] = __builtin_amdgcn_mfma_f32_16x16x32_bf16(kf, qf[1][c], st[1][kt], 0, 0, 0);
            }
        __builtin_amdgcn_s_setprio(0);
        bf16x8 vf[8];
        #pragma unroll
        for (int t = 0; t < 8; ++t)
            vf[t] = *(const bf16x8*)&Vl[buf][t * 16 + m][(kvsub + g * 8) ^ sw];
        #pragma unroll
        for (int qt = 0; qt < 2; ++qt) {
            unsigned pk[2][2];
            #pragma unroll
            for (int kt = 0; kt < 2; ++kt) {
                const float e0 = exp2f(st[qt][kt][0] * CEXP);
                const float e1 = exp2f(st[qt][kt][1] * CEXP);
                const float e2 = exp2f(st[qt][kt][2] * CEXP);
                const float e3 = exp2f(st[qt][kt][3] * CEXP);
                pk[kt][0] = cvt_pk_bf16(e0, e1);
                pk[kt][1] = cvt_pk_bf16(e2, e3);
            }
            const unsigned w0 = __shfl(pk[0][0], srcA, 64);
            const unsigned w1 = __shfl(pk[0][1], srcA, 64);
            const unsigned w2 = __shfl(pk[0][0], srcA + 16, 64);
            const unsigned w3 = __shfl(pk[0][1], srcA + 16, 64);
            const unsigned x0 = __shfl(pk[1][0], srcA, 64);
            const unsigned x1 = __shfl(pk[1][1], srcA, 64);
            const unsigned x2 = __shfl(pk[1][0], srcA + 16, 64);
            const unsigned x3 = __shfl(pk[1][1], srcA + 16, 64);
            union { unsigned u[4]; bf16x8 v; } af;
            af.u[0] = glo ? w0 : x0;
            af.u[1] = glo ? w1 : x1;
            af.u[2] = glo ? w2 : x2;
            af.u[3] = glo ? w3 : x3;
            __builtin_amdgcn_s_setprio(1);
            #pragma unroll
            for (int t = 0; t < 8; ++t)
                oacc[qt][t] = __builtin_amdgcn_mfma_f32_16x16x32_bf16(af.v, vf[t], oacc[qt][t], 0, 0, 0);
            acc_l[qt] = __builtin_amdgcn_mfma_f32_16x16x32_bf16(af.v, ones, acc_l[qt], 0, 0, 0);
            __builtin_amdgcn_s_setprio(0);
        }
    };

    STAGE(0, 0);                      // vmcnt: 8 outstanding
    int cur = 0;
    for (int t = 0; t < 16; ++t) {
        if (t < 15) {
            STAGE(cur ^ 1, t + 1);    // 16 outstanding
            WAITVN(8);                // tile t landed (mine); next stays in flight
        } else {
            WAITVN(0);
        }
        SBAR();                       // everyone's tile-t loads landed
        HALF(cur, 0);
        HALF(cur, 32);
        asm volatile("s_waitcnt lgkmcnt(0)" ::: "memory");
        SBAR();                       // all waves done reading buf[cur]
        cur ^= 1;
    }

    short* ob = O + ((long)b * Nn + q0) * Dd;
    #pragma unroll
    for (int qt = 0; qt < 2; ++qt)
        #pragma unroll
        for (int r = 0; r < 4; ++r) {
            const float inv = 1.0f / acc_l[qt][r];
            #pragma unroll
            for (int t = 0; t < 8; ++t)
                ob[(qt * 16 + 4 * g + r) * Dd + t * 16 + m] =
                    (short)f2bf(oacc[qt][t][r] * inv);
        }
}

// ---------------------------------------------------------------------------
// Kernel 3: MFMA fc1 (bf16) + relu + softmax + pooled*w. (r3 proven; A-frag
// reads now de-swizzle the d-half columns.)
__global__ __launch_bounds__(256, 2) void k_fuse(const float* __restrict__ drug1,
                                                 const float* __restrict__ drug2,
                                                 const short* __restrict__ d1s,
                                                 const short* __restrict__ d2s,
                                                 const short* __restrict__ layA,
                                                 const short* __restrict__ layB,
                                                 const float* __restrict__ fc1w,
                                                 const float* __restrict__ fc1b,
                                                 float* __restrict__ out) {
    const int tid = threadIdx.x, wave = tid >> 6, lane = tid & 63;
    const int m = lane & 15, g = lane >> 4;

    bf16x8 wb[4][8];
    #pragma unroll
    for (int t = 0; t < 4; ++t)
        #pragma unroll
        for (int c = 0; c < 8; ++c) {
            const float* wp = fc1w + (t * 16 + m) * 256 + c * 32 + g * 8;
            const float4 a = *(const float4*)wp;
            const float4 bq = *(const float4*)(wp + 4);
            union { unsigned u[4]; bf16x8 v; } pk;
            pk.u[0] = cvt_pk_bf16(a.x, a.y);
            pk.u[1] = cvt_pk_bf16(a.z, a.w);
            pk.u[2] = cvt_pk_bf16(bq.x, bq.y);
            pk.u[3] = cvt_pk_bf16(bq.z, bq.w);
            wb[t][c] = pk.v;
        }
    float bias[4];
    #pragma unroll
    for (int t = 0; t < 4; ++t) bias[t] = fc1b[t * 16 + m];

    #pragma unroll
    for (int cc = 0; cc < 2; ++cc) {
        const int row0 = blockIdx.x * 128 + cc * 64 + wave * 16;
        const int bb = row0 >> 11;
        const int i0 = row0 & 2047;
        const bool hf = (i0 >= Nn);
        const int ii = hf ? i0 - Nn : i0;
        const short* dsrc = (hf ? d2s : d1s) + ((long)bb * Nn + ii) * Dd;
        const short* lsrc = (hf ? layB : layA) + ((long)bb * Nn + ii) * Dd;
        const float* fsrc = (hf ? drug2 : drug1) + ((long)bb * Nn + ii) * Dd;

        f32x4 acc[4];
        #pragma unroll
        for (int t = 0; t < 4; ++t) acc[t] = (f32x4){0.f, 0.f, 0.f, 0.f};
        #pragma unroll
        for (int c = 0; c < 8; ++c) {
            const short* ap = (c < 4)
                ? dsrc + (long)m * Dd + ((c * 32 + g * 8) ^ ((m & 7) * 8))
                : lsrc + (long)m * Dd + (c - 4) * 32 + g * 8;
            const bf16x8 af = *(const bf16x8*)ap;
            #pragma unroll
            for (int t = 0; t < 4; ++t)
                acc[t] = __builtin_amdgcn_mfma_f32_16x16x32_bf16(af, wb[t][c], acc[t], 0, 0, 0);
        }
        #pragma unroll
        for (int r = 0; r < 4; ++r) {
            float v[4];
            #pragma unroll
            for (int t = 0; t < 4; ++t) v[t] = fmaxf(acc[t][r] + bias[t], 0.f);
            float mx = fmaxf(fmaxf(v[0], v[1]), fmaxf(v[2], v[3]));
            #pragma unroll
            for (int msk = 1; msk < 16; msk <<= 1)
                mx = fmaxf(mx, __shfl_xor(mx, msk, 64));
            float e[4], sum = 0.f;
            #pragma unroll
            for (int t = 0; t < 4; ++t) { e[t] = exp2f((v[t] - mx) * LOG2E); sum += e[t]; }
            #pragma unroll
            for (int msk = 1; msk < 16; msk <<= 1) sum += __shfl_xor(sum, msk, 64);
            const float rinv = 1.0f / sum;

            const int rr = 4 * g + r;
            const float* fr = fsrc + (long)rr * Dd;
            const short* lr = lsrc + (long)rr * Dd;
            const float4 d0 = *(const float4*)(fr + 4 * m);
            const float4 d1 = *(const float4*)(fr + 64 + 4 * m);
            float ss = d0.x*d0.x + d0.y*d0.y + d0.z*d0.z + d0.w*d0.w
                     + d1.x*d1.x + d1.y*d1.y + d1.z*d1.z + d1.w*d1.w;
            #pragma unroll
            for (int msk = 1; msk < 16; msk <<= 1) ss += __shfl_xor(ss, msk, 64);
            const float ninv = 1.0f / fmaxf(sqrtf(ss), 1e-12f);
            const short4 l0 = *(const short4*)(lr + 4 * m);
            const short4 l1 = *(const short4*)(lr + 64 + 4 * m);
            float pooled[4];
            pooled[0] = 0.25f * (d0.x + d0.y + d0.z + d0.w) * ninv;
            pooled[1] = 0.25f * (d1.x + d1.y + d1.z + d1.w) * ninv;
            pooled[2] = 0.25f * (bf2f(l0.x) + bf2f(l0.y) + bf2f(l0.z) + bf2f(l0.w));
            pooled[3] = 0.25f * (bf2f(l1.x) + bf2f(l1.y) + bf2f(l1.z) + bf2f(l1.w));
            float* op = out + ((long)row0 + rr) * OUTW;
            #pragma unroll
            for (int t = 0; t < 4; ++t) op[t * 16 + m] = pooled[t] * (e[t] * rinv);
        }
    }
}

// ---------------------------------------------------------------------------
extern "C" void kernel_launch(void* const* d_in, const int* in_sizes, int n_in,
                              void* d_out, int out_size, void* d_ws, size_t ws_size,
                              hipStream_t stream) {
    const float* drug1 = (const float*)d_in[0];
    const float* drug2 = (const float*)d_in[1];
    const float* fc1w  = (const float*)d_in[2];
    const float* fc1b  = (const float*)d_in[3];
    float* out = (float*)d_out;

    char* ws = (char*)d_ws;                        // 48 MB total (proven)
    short* d1s    = (short*)(ws);                  //  8 MB swizzled bf16 d1
    short* d2s    = (short*)(ws + 8388608);        //  8 MB swizzled bf16 d2
    short* d1ts   = (short*)(ws + 16777216);       //  8 MB swizzled transposed d1
    short* d2ts   = (short*)(ws + 25165824);       //  8 MB swizzled transposed d2
    short* layerA = (short*)(ws + 33554432);       //  8 MB bf16 drug2_layer
    short* layerB = (short*)(ws + 41943040);       //  8 MB bf16 drug1_layer

    hipLaunchKernelGGL(k_norm, dim3(16, 32, 2), dim3(256), 0, stream,
                       drug1, drug2, d1s, d2s, d1ts, d2ts);
    hipLaunchKernelGGL(k_attn, dim3(512), dim3(256), 0, stream,
                       d1s, d2s, d1ts, d2ts, layerA, layerB);
    hipLaunchKernelGGL(k_fuse, dim3(512), dim3(256), 0, stream,
                       drug1, drug2, d1s, d2s, layerA, layerB, fc1w, fc1b, out);
}

// Round 8
// 158.452 us; speedup vs baseline: 2.0326x; 1.0612x over previous
//
#include <hip/hip_runtime.h>

#define Bz   32
#define Nn   1024
#define Dd   128
#define OUTW 64
#define CEXP 0.72134752044448169f   // 0.5 * log2(e)
#define LOG2E 1.4426950408889634f

typedef __attribute__((ext_vector_type(8))) short bf16x8;   // 8 bf16 = 4 VGPR
typedef __attribute__((ext_vector_type(4))) short bf16x4;
typedef __attribute__((ext_vector_type(4))) float f32x4;
typedef __attribute__((ext_vector_type(16))) float f32x16;

static __device__ __forceinline__ unsigned short f2bf(float x) {
    unsigned u = __float_as_uint(x);
    u += 0x7FFFu + ((u >> 16) & 1u);            // RNE
    return (unsigned short)(u >> 16);
}
static __device__ __forceinline__ float bf2f(short b) {
    return __uint_as_float(((unsigned)(unsigned short)b) << 16);
}
static __device__ __forceinline__ unsigned cvt_pk_bf16(float lo, float hi) {
    unsigned r;
    asm("v_cvt_pk_bf16_f32 %0, %1, %2" : "=v"(r) : "v"(lo), "v"(hi));
    return r;
}
// a[32+i] <-> b[i]: after, a = [lo: a_lo | hi: b_lo-of-partner],
// b = [lo: a_hi-of-partner | hi: b_hi]   (T12 recipe ordering)
#define PLSWAP(a, b) asm("v_permlane32_swap_b32 %0, %1" : "+v"(a), "+v"(b))

// async global->LDS, 16B per lane; LDS dest = wave-uniform base + lane*16
#define GLL16(g, l) __builtin_amdgcn_global_load_lds( \
    (const __attribute__((address_space(1))) unsigned*)(const void*)(g), \
    (__attribute__((address_space(3))) unsigned*)(void*)(l), 16, 0, 0)
#define WAITVN(n) { asm volatile("s_waitcnt vmcnt(" #n ")" ::: "memory"); \
                    __builtin_amdgcn_sched_barrier(0); }
#define SBAR() __builtin_amdgcn_s_barrier()

// Global bf16 arrays carry a T2 swizzle: element [n][d] stored at
// [n][d ^ ((n&7)*8)] (row-major) / [d][kv ^ ((d&7)*8)] within each 64-aligned
// kv window (transposed). XOR acts on 16B chunks -> vector ops stay aligned.

// ---------------------------------------------------------------------------
// Kernel 1: L2-normalize + swizzled bf16 row-major AND transposed copies.
__global__ __launch_bounds__(256) void k_norm(const float* __restrict__ drug1,
                                              const float* __restrict__ drug2,
                                              short* __restrict__ d1s,
                                              short* __restrict__ d2s,
                                              short* __restrict__ d1ts,
                                              short* __restrict__ d2ts) {
    __shared__ __attribute__((aligned(16))) short T[Dd * 64];   // 16 KB
    const int tid = threadIdx.x, wave = tid >> 6, lane = tid & 63;
    const int b = blockIdx.y;
    const int n0 = blockIdx.x * 64;
    const float* src; short* dstR; short* dstT;
    if (blockIdx.z == 0) { src = drug1; dstR = d1s; dstT = d1ts; }
    else                 { src = drug2; dstR = d2s; dstT = d2ts; }

    const int rh = lane >> 5;          // 0/1: which row of the pair
    const int c  = lane & 31;          // float4 chunk within the row
    #pragma unroll
    for (int i = 0; i < 8; ++i) {
        const int col = wave * 16 + i * 2 + rh;       // 0..63 tile row
        const int n = n0 + col;
        const float4 v = *(const float4*)(src + ((long)b * Nn + n) * Dd + c * 4);
        float ss = v.x * v.x + v.y * v.y + v.z * v.z + v.w * v.w;
        #pragma unroll
        for (int msk = 1; msk < 32; msk <<= 1) ss += __shfl_xor(ss, msk, 64);
        const float inv = 1.0f / fmaxf(sqrtf(ss), 1e-12f);
        const unsigned p0 = cvt_pk_bf16(v.x * inv, v.y * inv);
        const unsigned p1 = cvt_pk_bf16(v.z * inv, v.w * inv);
        uint2 u2; u2.x = p0; u2.y = p1;
        *(uint2*)(dstR + ((long)b * Nn + n) * Dd + ((c * 4) ^ ((n & 7) * 8))) = u2;
        const unsigned short e0 = (unsigned short)(p0 & 0xFFFF);
        const unsigned short e1 = (unsigned short)(p0 >> 16);
        const unsigned short e2 = (unsigned short)(p1 & 0xFFFF);
        const unsigned short e3 = (unsigned short)(p1 >> 16);
        const int Csw = (16 * (c >> 3)) ^ (8 * (c & 3));
        const int pc = col ^ Csw;
        T[(c * 4 + 0) * 64 + pc] = (short)e0;
        T[(c * 4 + 1) * 64 + pc] = (short)e1;
        T[(c * 4 + 2) * 64 + pc] = (short)e2;
        T[(c * 4 + 3) * 64 + pc] = (short)e3;
    }
    __syncthreads();
    const int d = tid >> 1, h = tid & 1;
    const int C = (16 * (d >> 5)) ^ (8 * ((d >> 2) & 3));
    short* wtp = dstT + ((long)b * Dd + d) * Nn + n0;
    #pragma unroll
    for (int k = 0; k < 4; ++k) {
        const int gi = h * 4 + k;
        *(bf16x8*)(wtp + ((gi ^ (d & 7)) * 8)) =
            *(const bf16x8*)&T[d * 64 + ((gi * 8) ^ C)];
    }
}

// ---------------------------------------------------------------------------
// Kernel 2: dual-direction attention, 32x32x16 MFMA + permlane P-routing.
// Block = 4 waves x 32 q-rows; KV tile 64 double-buffered via global_load_lds.
__global__ __launch_bounds__(256, 2) void k_attn(const short* __restrict__ d1s,
                                                 const short* __restrict__ d2s,
                                                 const short* __restrict__ d1ts,
                                                 const short* __restrict__ d2ts,
                                                 short* __restrict__ layerA,
                                                 short* __restrict__ layerB) {
    __shared__ __attribute__((aligned(16))) short Kl[2][64][128];  // 32 KB
    __shared__ __attribute__((aligned(16))) short Vl[2][128][64];  // 32 KB

    const int bid = blockIdx.x;            // XCD-aware remap (proven r3)
    const int xcd = bid & 7, tt = bid >> 3;
    const int jq = tt & 7, gq = tt >> 3;
    const int grp = xcd + 8 * gq;          // (b, z)
    const int b = grp & 31, z = grp >> 5;

    const int tid = threadIdx.x, wave = tid >> 6, lane = tid & 63;
    const int r31 = lane & 31, h8 = lane >> 5, r7 = lane & 7;
    const short *Q, *Ks, *Vts; short* O;
    if (z == 0) { Q = d1s; Ks = d2s; Vts = d2ts; O = layerA; }
    else        { Q = d2s; Ks = d1s; Vts = d1ts; O = layerB; }
    const int q0 = jq * 128 + wave * 32;

    // Q B-frags: lane holds Q[q0+r31][c*16 + h8*8 + j] (de-swizzled)
    const short* Qb = Q + ((long)b * Nn + q0) * Dd;
    bf16x8 qf[8];
    #pragma unroll
    for (int c = 0; c < 8; ++c)
        qf[c] = *(const bf16x8*)(Qb + (long)r31 * Dd + (((2 * c + h8) ^ r7) * 8));

    f32x16 oacc[4];
    #pragma unroll
    for (int dblk = 0; dblk < 4; ++dblk)
        #pragma unroll
        for (int r = 0; r < 16; ++r) oacc[dblk][r] = 0.f;
    float lsum = 0.f;

    const short* Ksb = Ks  + (long)b * Nn * Dd;
    const short* Vtb = Vts + (long)b * Dd * Nn;
    const int klr = lane >> 4, klc = lane & 15;
    const int vlr = lane >> 3, vlc = lane & 7;

    auto STAGE = [&](int buf, int tile) {
        const int kv0 = tile * 64;
        #pragma unroll
        for (int j = 0; j < 4; ++j)
            GLL16(Ksb + ((long)(kv0 + wave * 16 + j * 4 + klr)) * Dd + klc * 8,
                  &Kl[buf][wave * 16 + j * 4][0]);
        #pragma unroll
        for (int j = 0; j < 4; ++j)
            GLL16(Vtb + ((long)(wave * 32 + j * 8 + vlr)) * Nn + kv0 + vlc * 8,
                  &Vl[buf][wave * 32 + j * 8][0]);
    };

    auto SUB = [&](int buf, int sub) {
        // ---- S' = K·Q^T (32 kv x 32 q), D: lane holds 16 kv for q=r31 ----
        f32x16 st;
        #pragma unroll
        for (int r = 0; r < 16; ++r) st[r] = 0.f;
        __builtin_amdgcn_s_setprio(1);
        #pragma unroll
        for (int c = 0; c < 8; ++c) {
            const bf16x8 kf = *(const bf16x8*)
                &Kl[buf][sub * 32 + r31][((2 * c + h8) ^ r7) * 8];
            st = __builtin_amdgcn_mfma_f32_32x32x16_bf16(kf, qf[c], st, 0, 0, 0);
        }
        __builtin_amdgcn_s_setprio(0);
        // ---- V B-frags (issue early; latency hides under softmax VALU) ----
        bf16x8 vf[2][4];
        #pragma unroll
        for (int kvh = 0; kvh < 2; ++kvh)
            #pragma unroll
            for (int dblk = 0; dblk < 4; ++dblk)
                vf[kvh][dblk] = *(const bf16x8*)
                    &Vl[buf][dblk * 32 + r31][((4 * sub + 2 * kvh + h8) ^ r7) * 8];
        // ---- P = exp(0.5*S); in-lane row-sum; pack+permlane to A-frags ----
        float p[16];
        #pragma unroll
        for (int r = 0; r < 16; ++r) p[r] = exp2f(st[r] * CEXP);
        float s4[4];
        #pragma unroll
        for (int k = 0; k < 4; ++k)
            s4[k] = (p[4 * k] + p[4 * k + 1]) + (p[4 * k + 2] + p[4 * k + 3]);
        lsum += (s4[0] + s4[1]) + (s4[2] + s4[3]);
        unsigned u0 = cvt_pk_bf16(p[0], p[1]),  u1 = cvt_pk_bf16(p[2], p[3]);
        unsigned u2 = cvt_pk_bf16(p[4], p[5]),  u3 = cvt_pk_bf16(p[6], p[7]);
        unsigned u4 = cvt_pk_bf16(p[8], p[9]),  u5 = cvt_pk_bf16(p[10], p[11]);
        unsigned u6 = cvt_pk_bf16(p[12], p[13]), u7 = cvt_pk_bf16(p[14], p[15]);
        PLSWAP(u0, u2); PLSWAP(u1, u3);   // frag0: kv sub*32 + 0..15
        PLSWAP(u4, u6); PLSWAP(u5, u7);   // frag1: kv sub*32 + 16..31
        union { unsigned u[4]; bf16x8 v; } f0, f1;
        f0.u[0] = u0; f0.u[1] = u1; f0.u[2] = u2; f0.u[3] = u3;
        f1.u[0] = u4; f1.u[1] = u5; f1.u[2] = u6; f1.u[3] = u7;
        // ---- O += P·V ----
        __builtin_amdgcn_s_setprio(1);
        #pragma unroll
        for (int dblk = 0; dblk < 4; ++dblk)
            oacc[dblk] = __builtin_amdgcn_mfma_f32_32x32x16_bf16(f0.v, vf[0][dblk], oacc[dblk], 0, 0, 0);
        #pragma unroll
        for (int dblk = 0; dblk < 4; ++dblk)
            oacc[dblk] = __builtin_amdgcn_mfma_f32_32x32x16_bf16(f1.v, vf[1][dblk], oacc[dblk], 0, 0, 0);
        __builtin_amdgcn_s_setprio(0);
    };

    STAGE(0, 0);
    int cur = 0;
    for (int t = 0; t < 16; ++t) {
        if (t < 15) {
            STAGE(cur ^ 1, t + 1);
            WAITVN(8);                // my tile-t loads landed; next in flight
        } else {
            WAITVN(0);
        }
        SBAR();
        SUB(cur, 0);
        SUB(cur, 1);
        asm volatile("s_waitcnt lgkmcnt(0)" ::: "memory");
        SBAR();
        cur ^= 1;
    }

    // rowsum[q=r31] = own half + partner half
    const float tot = lsum + __shfl_xor(lsum, 32, 64);
    const float rinv = 1.0f / tot;
    short* ob = O + ((long)b * Nn + q0) * Dd;
    #pragma unroll
    for (int r = 0; r < 16; ++r) {
        const int qq = (r & 3) + 8 * (r >> 2) + 4 * h8;
        const float inv = __shfl(rinv, qq, 64);
        #pragma unroll
        for (int dblk = 0; dblk < 4; ++dblk)
            ob[qq * Dd + dblk * 32 + r31] = (short)f2bf(oacc[dblk][r] * inv);
    }
}

// ---------------------------------------------------------------------------
// Kernel 3: MFMA fc1 + relu + softmax + pooled*w. pooled now fully from bf16
// (w <= ~0.02 makes bf16 pooled error negligible); no fp32 drug reads.
__global__ __launch_bounds__(256, 2) void k_fuse(const short* __restrict__ d1s,
                                                 const short* __restrict__ d2s,
                                                 const short* __restrict__ layA,
                                                 const short* __restrict__ layB,
                                                 const float* __restrict__ fc1w,
                                                 const float* __restrict__ fc1b,
                                                 float* __restrict__ out) {
    const int tid = threadIdx.x, wave = tid >> 6, lane = tid & 63;
    const int m = lane & 15, g = lane >> 4;

    bf16x8 wb[4][8];
    #pragma unroll
    for (int t = 0; t < 4; ++t)
        #pragma unroll
        for (int c = 0; c < 8; ++c) {
            const float* wp = fc1w + (t * 16 + m) * 256 + c * 32 + g * 8;
            const float4 a = *(const float4*)wp;
            const float4 bq = *(const float4*)(wp + 4);
            union { unsigned u[4]; bf16x8 v; } pk;
            pk.u[0] = cvt_pk_bf16(a.x, a.y);
            pk.u[1] = cvt_pk_bf16(a.z, a.w);
            pk.u[2] = cvt_pk_bf16(bq.x, bq.y);
            pk.u[3] = cvt_pk_bf16(bq.z, bq.w);
            wb[t][c] = pk.v;
        }
    float bias[4];
    #pragma unroll
    for (int t = 0; t < 4; ++t) bias[t] = fc1b[t * 16 + m];

    #pragma unroll
    for (int cc = 0; cc < 2; ++cc) {
        const int row0 = blockIdx.x * 128 + cc * 64 + wave * 16;
        const int bb = row0 >> 11;
        const int i0 = row0 & 2047;
        const bool hf = (i0 >= Nn);
        const int ii = hf ? i0 - Nn : i0;
        const short* dsrc = (hf ? d2s : d1s) + ((long)bb * Nn + ii) * Dd;
        const short* lsrc = (hf ? layB : layA) + ((long)bb * Nn + ii) * Dd;

        f32x4 acc[4];
        #pragma unroll
        for (int t = 0; t < 4; ++t) acc[t] = (f32x4){0.f, 0.f, 0.f, 0.f};
        #pragma unroll
        for (int c = 0; c < 8; ++c) {
            const short* ap = (c < 4)
                ? dsrc + (long)m * Dd + ((c * 32 + g * 8) ^ ((m & 7) * 8))
                : lsrc + (long)m * Dd + (c - 4) * 32 + g * 8;
            const bf16x8 af = *(const bf16x8*)ap;
            #pragma unroll
            for (int t = 0; t < 4; ++t)
                acc[t] = __builtin_amdgcn_mfma_f32_16x16x32_bf16(af, wb[t][c], acc[t], 0, 0, 0);
        }
        #pragma unroll
        for (int r = 0; r < 4; ++r) {
            float v[4];
            #pragma unroll
            for (int t = 0; t < 4; ++t) v[t] = fmaxf(acc[t][r] + bias[t], 0.f);
            float mx = fmaxf(fmaxf(v[0], v[1]), fmaxf(v[2], v[3]));
            #pragma unroll
            for (int msk = 1; msk < 16; msk <<= 1)
                mx = fmaxf(mx, __shfl_xor(mx, msk, 64));
            float e[4], sum = 0.f;
            #pragma unroll
            for (int t = 0; t < 4; ++t) { e[t] = exp2f((v[t] - mx) * LOG2E); sum += e[t]; }
            #pragma unroll
            for (int msk = 1; msk < 16; msk <<= 1) sum += __shfl_xor(sum, msk, 64);
            const float rinv = 1.0f / sum;

            const int rr = 4 * g + r;
            const short* dr = dsrc + (long)rr * Dd;
            const short* lr = lsrc + (long)rr * Dd;
            float pooled[4];
            #pragma unroll
            for (int t = 0; t < 2; ++t) {
                const int e0 = t * 64 + 4 * m;
                const int phys = (((e0 >> 3) ^ (rr & 7)) * 8) + (e0 & 7);
                const short4 s4 = *(const short4*)(dr + phys);
                pooled[t] = 0.25f * (bf2f(s4.x) + bf2f(s4.y) + bf2f(s4.z) + bf2f(s4.w));
            }
            #pragma unroll
            for (int t = 2; t < 4; ++t) {
                const short4 s4 = *(const short4*)(lr + (t - 2) * 64 + 4 * m);
                pooled[t] = 0.25f * (bf2f(s4.x) + bf2f(s4.y) + bf2f(s4.z) + bf2f(s4.w));
            }
            float* op = out + ((long)row0 + rr) * OUTW;
            #pragma unroll
            for (int t = 0; t < 4; ++t) op[t * 16 + m] = pooled[t] * (e[t] * rinv);
        }
    }
}

// ---------------------------------------------------------------------------
extern "C" void kernel_launch(void* const* d_in, const int* in_sizes, int n_in,
                              void* d_out, int out_size, void* d_ws, size_t ws_size,
                              hipStream_t stream) {
    const float* drug1 = (const float*)d_in[0];
    const float* drug2 = (const float*)d_in[1];
    const float* fc1w  = (const float*)d_in[2];
    const float* fc1b  = (const float*)d_in[3];
    float* out = (float*)d_out;

    char* ws = (char*)d_ws;                        // 48 MB total (proven)
    short* d1s    = (short*)(ws);                  //  8 MB swizzled bf16 d1
    short* d2s    = (short*)(ws + 8388608);        //  8 MB swizzled bf16 d2
    short* d1ts   = (short*)(ws + 16777216);       //  8 MB swizzled transposed d1
    short* d2ts   = (short*)(ws + 25165824);       //  8 MB swizzled transposed d2
    short* layerA = (short*)(ws + 33554432);       //  8 MB bf16 drug2_layer
    short* layerB = (short*)(ws + 41943040);       //  8 MB bf16 drug1_layer

    hipLaunchKernelGGL(k_norm, dim3(16, 32, 2), dim3(256), 0, stream,
                       drug1, drug2, d1s, d2s, d1ts, d2ts);
    hipLaunchKernelGGL(k_attn, dim3(512), dim3(256), 0, stream,
                       d1s, d2s, d1ts, d2ts, layerA, layerB);
    hipLaunchKernelGGL(k_fuse, dim3(512), dim3(256), 0, stream,
                       d1s, d2s, layerA, layerB, fc1w, fc1b, out);
}